// Round 7
// baseline (708.969 us; speedup 1.0000x reference)
//
#include <hip/hip_runtime.h>
#include <hip/hip_bf16.h>
#include <math.h>

typedef __hip_bfloat16 bf16;
typedef short bf16x8 __attribute__((ext_vector_type(8)));
typedef short short4v __attribute__((ext_vector_type(4)));
typedef float f32x4 __attribute__((ext_vector_type(4)));

#define D_MODEL 256
#define NTOK 1024
#define SEQ 1022
#define BATCH 4
#define NLAYER 6

// ---- async global->LDS 16B helper ----
__device__ inline void gload_lds16(const void* g, void* l) {
    __builtin_amdgcn_global_load_lds(
        (const __attribute__((address_space(1))) void*)g,
        (__attribute__((address_space(3))) void*)l, 16, 0, 0);
}

// ---------------- merged weight fp32 -> bf16 cast (4 tensors, 1 launch) ----------------
__global__ __launch_bounds__(256) void cast4_kernel(
    const float* __restrict__ s0, bf16* __restrict__ d0,   // 1,179,648
    const float* __restrict__ s1, bf16* __restrict__ d1,   //   393,216
    const float* __restrict__ s2, bf16* __restrict__ d2,   // 3,145,728
    const float* __restrict__ s3, bf16* __restrict__ d3)   // 3,145,728
{
    const int bid = blockIdx.x;
    const float* s; bf16* d; int base;
    if (bid < 1152)      { s = s0; d = d0; base = bid; }
    else if (bid < 1536) { s = s1; d = d1; base = bid - 1152; }
    else if (bid < 4608) { s = s2; d = d2; base = bid - 1536; }
    else                 { s = s3; d = d3; base = bid - 4608; }
    const int i = (base * 256 + threadIdx.x) * 4;
    f32x4 v = *(const f32x4*)(s + i);
    d[i + 0] = __float2bfloat16(v[0]);
    d[i + 1] = __float2bfloat16(v[1]);
    d[i + 2] = __float2bfloat16(v[2]);
    d[i + 3] = __float2bfloat16(v[3]);
}

// ---------------- embed ----------------
__global__ __launch_bounds__(256) void embed_kernel(
    const float* __restrict__ x, const float* __restrict__ cls1,
    const float* __restrict__ cls2, const int* __restrict__ ind,
    float* __restrict__ h, bf16* __restrict__ hb)
{
    int i = blockIdx.x * 256 + threadIdx.x;
    int d = i & 255;
    int pos = (i >> 8) & 1023;
    int b = i >> 18;
    int idx = ind[b];
    float v;
    if (pos == 0) v = cls1[d];
    else if (pos == idx + 1) v = cls2[d];
    else if (pos <= idx) v = x[(b * SEQ + pos - 1) * D_MODEL + d];
    else v = x[(b * SEQ + pos - 2) * D_MODEL + d];
    int p = d >> 1;
    float freq = expf(-(float)p * (logf(10000.0f) / 128.0f));
    float ang = (float)pos * freq;
    v += (d & 1) ? cosf(ang) : sinf(ang);
    h[i] = v;
    hb[i] = __float2bfloat16(v);
}

// ---------------- bf16 MFMA NT GEMM (layer-0 qkv / W1) ----------------
template<int MR, int NR, int RELU, int HAS_RES, int WF32, int WBF16, int WVT>
__global__ __launch_bounds__(256) void mfma_gemm(
    const bf16* __restrict__ A, const bf16* __restrict__ W,
    const float* __restrict__ bias, const float* __restrict__ R,
    float* __restrict__ Cf, bf16* __restrict__ Cb, bf16* __restrict__ vTb,
    int M, int N, int K)
{
    constexpr int BM = MR * 32, BN = NR * 32;
    constexpr int ACH = BM * 4;
    constexpr int BCH = BN * 4;
    __shared__ bf16 As[2][BM * 32];
    __shared__ bf16 Bs[2][BN * 32];
    const int ntile = N / BN;
    const int bx = blockIdx.x % ntile, by = blockIdx.x / ntile;
    const int row0 = by * BM, col0 = bx * BN;
    const int tid = threadIdx.x, lane = tid & 63, wave = tid >> 6;
    const int wr = wave >> 1, wc = wave & 1;
    const int l15 = lane & 15, l4 = lane >> 4;

    f32x4 acc[MR][NR];
    #pragma unroll
    for (int m = 0; m < MR; ++m)
        #pragma unroll
        for (int n = 0; n < NR; ++n) acc[m][n] = (f32x4)0.0f;

    const int nk = K / 32;

    auto stage = [&](int buf, int t) {
        const int k0 = t * 32;
        #pragma unroll
        for (int p = 0; p < ACH / 256; ++p) {
            const int cbase = p * 256 + wave * 64;
            const int chunk = cbase + lane;
            const int r = chunk >> 2, c = chunk & 3;
            gload_lds16(A + (size_t)(row0 + r) * K + k0 + c * 8, &As[buf][cbase * 8]);
        }
        #pragma unroll
        for (int p = 0; p < BCH / 256; ++p) {
            const int cbase = p * 256 + wave * 64;
            const int chunk = cbase + lane;
            const int r = chunk >> 2, c = chunk & 3;
            gload_lds16(W + (size_t)(col0 + r) * K + k0 + c * 8, &Bs[buf][cbase * 8]);
        }
    };

    stage(0, 0);
    __syncthreads();
    int cur = 0;
    for (int t = 0; t < nk; ++t) {
        if (t + 1 < nk) stage(cur ^ 1, t + 1);
        bf16x8 af[MR], bfr[NR];
        #pragma unroll
        for (int m = 0; m < MR; ++m)
            af[m] = *(const bf16x8*)&As[cur][(wr * MR * 16 + m * 16 + l15) * 32 + l4 * 8];
        #pragma unroll
        for (int n = 0; n < NR; ++n)
            bfr[n] = *(const bf16x8*)&Bs[cur][(wc * NR * 16 + n * 16 + l15) * 32 + l4 * 8];
        #pragma unroll
        for (int m = 0; m < MR; ++m)
            #pragma unroll
            for (int n = 0; n < NR; ++n)
                acc[m][n] = __builtin_amdgcn_mfma_f32_16x16x32_bf16(af[m], bfr[n], acc[m][n], 0, 0, 0);
        __syncthreads();
        cur ^= 1;
    }

    #pragma unroll
    for (int m = 0; m < MR; ++m) {
        #pragma unroll
        for (int n = 0; n < NR; ++n) {
            const int col = col0 + wc * NR * 16 + n * 16 + l15;
            const float bv = bias[col];
            #pragma unroll
            for (int r = 0; r < 4; ++r) {
                const int row = row0 + wr * MR * 16 + m * 16 + l4 * 4 + r;
                float v = acc[m][n][r] + bv;
                if (HAS_RES) v += R[(size_t)row * N + col];
                if (RELU) v = fmaxf(v, 0.0f);
                if (WF32) Cf[(size_t)row * N + col] = v;
                if (WBF16) {
                    if (WVT && col >= 512) {
                        const int hh = (col >> 5) - 16, d = col & 31;
                        const int bb = row >> 10, tt = row & 1023;
                        vTb[(((size_t)bb * 8 + hh) * 32 + d) * 1024 + tt] = __float2bfloat16(v);
                    } else {
                        Cb[(size_t)row * N + col] = __float2bfloat16(v);
                    }
                }
            }
        }
    }
}

// ---------------- FUSED: attention + Wo + bias + residual + LayerNorm1 ----------------
// grid: B*64 blocks (16 token-rows each), 512 threads = 8 waves; wave = head.
// Attention: barrier-free per-wave loop (Q/K direct global, V from vT, P in
// wave-private LDS). Then O->LDS, Wo K-split 8-ways, 2-phase reduce, fused LN.
__global__ __launch_bounds__(512) void attn_wo_ln_kernel(
    const bf16* __restrict__ qkvb, const bf16* __restrict__ vT,
    const bf16* __restrict__ Wo, const float* __restrict__ bo,
    const float* __restrict__ g, const float* __restrict__ be,
    float* __restrict__ h, bf16* __restrict__ hb, const int* __restrict__ ind)
{
    __shared__ bf16 Ps[8][16][72];
    __shared__ bf16 att_s[16][264];
    __shared__ float part[4][16][260];
    const int qt = blockIdx.x & 63;
    const int b  = blockIdx.x >> 6;
    const int idx = ind[b];
    const int segEnd = NTOK - ind[4 + b];
    const int tid = threadIdx.x, lane = tid & 63, hh = tid >> 6;   // wave = head
    const int l15 = lane & 15, l4 = lane >> 4;
    const int q0 = qt * 16;
    const size_t tokbase = (size_t)b * NTOK;
    const bf16* vTh = vT + (((size_t)b * 8 + hh) * 32) * 1024;
    const float scale = 0.17677669529663687f;

    const bf16x8 qfrag = *(const bf16x8*)(qkvb + (tokbase + q0 + l15) * 768 + hh * 32 + l4 * 8);

    f32x4 acc_o[2];
    acc_o[0] = (f32x4)0.0f; acc_o[1] = (f32x4)0.0f;
    float mrun[4], lrun[4];
    bool v1q[4], v2q[4];
    #pragma unroll
    for (int r = 0; r < 4; ++r) {
        mrun[r] = -1e30f; lrun[r] = 0.0f;
        const int qg = q0 + l4 * 4 + r;
        v1q[r] = (qg <= idx);
        v2q[r] = (qg > idx) && (qg < segEnd);
    }

    const int kbeg = (q0 <= idx) ? 0 : (idx + 1);
    const int kend = (q0 + 15 > idx) ? segEnd : (idx + 1);

    for (int k0 = (kbeg & ~63); k0 < kend; k0 += 64) {
        f32x4 sc[4];
        #pragma unroll
        for (int kt = 0; kt < 4; ++kt) {
            const bf16x8 kf = *(const bf16x8*)
                (qkvb + (tokbase + k0 + kt * 16 + l15) * 768 + 256 + hh * 32 + l4 * 8);
            sc[kt] = __builtin_amdgcn_mfma_f32_16x16x32_bf16(qfrag, kf, (f32x4)0.0f, 0, 0, 0);
        }
        float mloc[4] = {-1e30f, -1e30f, -1e30f, -1e30f};
        #pragma unroll
        for (int kt = 0; kt < 4; ++kt) {
            const int k = k0 + kt * 16 + l15;
            const bool v1k = (k <= idx);
            const bool v2k = (k > idx) && (k < segEnd);
            #pragma unroll
            for (int r = 0; r < 4; ++r) {
                const bool ok = (v1q[r] && v1k) || (v2q[r] && v2k);
                const float s = ok ? sc[kt][r] * scale : -1e30f;
                sc[kt][r] = s;
                mloc[r] = fmaxf(mloc[r], s);
            }
        }
        #pragma unroll
        for (int r = 0; r < 4; ++r) {
            mloc[r] = fmaxf(mloc[r], __shfl_xor(mloc[r], 1));
            mloc[r] = fmaxf(mloc[r], __shfl_xor(mloc[r], 2));
            mloc[r] = fmaxf(mloc[r], __shfl_xor(mloc[r], 4));
            mloc[r] = fmaxf(mloc[r], __shfl_xor(mloc[r], 8));
            const float mnew = fmaxf(mrun[r], mloc[r]);
            const float c = __expf(mrun[r] - mnew);
            mrun[r] = mnew;
            mloc[r] = c;            // corr
        }
        float psum[4] = {0.0f, 0.0f, 0.0f, 0.0f};
        #pragma unroll
        for (int kt = 0; kt < 4; ++kt) {
            #pragma unroll
            for (int r = 0; r < 4; ++r) {
                const float s = sc[kt][r];
                const float p = (s > -5e29f) ? __expf(s - mrun[r]) : 0.0f;
                psum[r] += p;
                Ps[hh][l4 * 4 + r][kt * 16 + l15] = __float2bfloat16(p);
            }
        }
        #pragma unroll
        for (int r = 0; r < 4; ++r) {
            float ps = psum[r];
            ps += __shfl_xor(ps, 1); ps += __shfl_xor(ps, 2);
            ps += __shfl_xor(ps, 4); ps += __shfl_xor(ps, 8);
            lrun[r] = lrun[r] * mloc[r] + ps;
            acc_o[0][r] *= mloc[r];
            acc_o[1][r] *= mloc[r];
        }
        #pragma unroll
        for (int ks = 0; ks < 2; ++ks) {
            const bf16x8 pa = *(const bf16x8*)&Ps[hh][l15][ks * 32 + l4 * 8];
            #pragma unroll
            for (int dt = 0; dt < 2; ++dt) {
                const bf16x8 vb = *(const bf16x8*)
                    (vTh + (size_t)(dt * 16 + l15) * 1024 + k0 + ks * 32 + l4 * 8);
                acc_o[dt] = __builtin_amdgcn_mfma_f32_16x16x32_bf16(pa, vb, acc_o[dt], 0, 0, 0);
            }
        }
    }

    // O -> LDS (head hh owns cols [hh*32, hh*32+32))
    #pragma unroll
    for (int r = 0; r < 4; ++r) {
        const float invl = (lrun[r] > 0.0f) ? (1.0f / lrun[r]) : 0.0f;
        att_s[l4 * 4 + r][hh * 32 + l15]      = __float2bfloat16(acc_o[0][r] * invl);
        att_s[l4 * 4 + r][hh * 32 + 16 + l15] = __float2bfloat16(acc_o[1][r] * invl);
    }
    __syncthreads();

    // Wo: wave hh handles k-slice [hh*32, hh*32+32)
    f32x4 wacc[16];
    #pragma unroll
    for (int n = 0; n < 16; ++n) wacc[n] = (f32x4)0.0f;
    {
        const bf16x8 af = *(const bf16x8*)&att_s[l15][hh * 32 + l4 * 8];
        #pragma unroll
        for (int n = 0; n < 16; ++n) {
            const bf16x8 bfr = *(const bf16x8*)(Wo + (size_t)(n * 16 + l15) * 256 + hh * 32 + l4 * 8);
            wacc[n] = __builtin_amdgcn_mfma_f32_16x16x32_bf16(af, bfr, wacc[n], 0, 0, 0);
        }
    }
    if (hh < 4) {
        #pragma unroll
        for (int n = 0; n < 16; ++n)
            #pragma unroll
            for (int r = 0; r < 4; ++r)
                part[hh][l4 * 4 + r][n * 16 + l15] = wacc[n][r];
    }
    __syncthreads();
    if (hh >= 4) {
        #pragma unroll
        for (int n = 0; n < 16; ++n)
            #pragma unroll
            for (int r = 0; r < 4; ++r)
                part[hh - 4][l4 * 4 + r][n * 16 + l15] += wacc[n][r];
    }
    __syncthreads();

    // epilogue: thread -> (row = tid>>5, 8 cols at (tid&31)*8); bias+res+LN
    const int row = tid >> 5, c8 = (tid & 31) * 8;
    f32x4 v0, v1;
    v0 = *(const f32x4*)&part[0][row][c8];
    v1 = *(const f32x4*)&part[0][row][c8 + 4];
    #pragma unroll
    for (int w = 1; w < 4; ++w) {
        v0 += *(const f32x4*)&part[w][row][c8];
        v1 += *(const f32x4*)&part[w][row][c8 + 4];
    }
    float* hrow = h + (tokbase + q0 + row) * 256 + c8;
    v0 += *(const f32x4*)(bo + c8)     + *(const f32x4*)(hrow);
    v1 += *(const f32x4*)(bo + c8 + 4) + *(const f32x4*)(hrow + 4);
    float s1 = (v0[0] + v0[1]) + (v0[2] + v0[3]) + (v1[0] + v1[1]) + (v1[2] + v1[3]);
    #pragma unroll
    for (int off = 16; off >= 1; off >>= 1) s1 += __shfl_xor(s1, off);
    const float mu = s1 * (1.0f / 256.0f);
    float s2 = 0.0f;
    #pragma unroll
    for (int q = 0; q < 4; ++q) { float d0 = v0[q] - mu, d1 = v1[q] - mu; s2 += d0 * d0 + d1 * d1; }
    #pragma unroll
    for (int off = 16; off >= 1; off >>= 1) s2 += __shfl_xor(s2, off);
    const float inv = 1.0f / sqrtf(s2 * (1.0f / 256.0f) + 1e-5f);
    short* hbrow = (short*)hb + (tokbase + q0 + row) * 256 + c8;
    const f32x4 gv0 = *(const f32x4*)(g + c8),  gv1 = *(const f32x4*)(g + c8 + 4);
    const f32x4 ev0 = *(const f32x4*)(be + c8), ev1 = *(const f32x4*)(be + c8 + 4);
    f32x4 y0, y1; short4v p0, p1;
    #pragma unroll
    for (int q = 0; q < 4; ++q) {
        y0[q] = (v0[q] - mu) * inv * gv0[q] + ev0[q];
        y1[q] = (v1[q] - mu) * inv * gv1[q] + ev1[q];
        p0[q] = __builtin_bit_cast(short, __float2bfloat16(y0[q]));
        p1[q] = __builtin_bit_cast(short, __float2bfloat16(y1[q]));
    }
    *(f32x4*)(hrow) = y0;  *(f32x4*)(hrow + 4) = y1;
    *(short4v*)(hbrow) = p0;  *(short4v*)(hbrow + 4) = p1;
}

// ---------------- FUSED: W2 + bias + residual + LayerNorm2 + next-layer QKV ----------------
// grid: M/16 = 256 blocks, 512 threads = 8 waves. W2 K-split 8-ways; 2-phase
// reduce; LN; then qkv GEMM (K=256) reading LN output from LDS; vT scatter.
template<int SKIPQKV>
__global__ __launch_bounds__(512) void w2ln_qkv_kernel(
    const bf16* __restrict__ ffb, const bf16* __restrict__ W2,
    const float* __restrict__ b2, const float* __restrict__ g,
    const float* __restrict__ be, float* __restrict__ h, bf16* __restrict__ hb,
    const bf16* __restrict__ Wq, const float* __restrict__ bq,
    bf16* __restrict__ qkvb, bf16* __restrict__ vTb)
{
    __shared__ float part[4][16][260];
    __shared__ bf16 hbuf[16][264];
    const int tid = threadIdx.x, lane = tid & 63, wave = tid >> 6;
    const int l15 = lane & 15, l4 = lane >> 4;
    const int row0 = blockIdx.x * 16;

    f32x4 acc[16];
    #pragma unroll
    for (int n = 0; n < 16; ++n) acc[n] = (f32x4)0.0f;
    #pragma unroll
    for (int s = 0; s < 8; ++s) {
        const int kk = wave * 256 + s * 32;
        const bf16x8 af = *(const bf16x8*)(ffb + (size_t)(row0 + l15) * 2048 + kk + l4 * 8);
        #pragma unroll
        for (int n = 0; n < 16; ++n) {
            const bf16x8 bfr = *(const bf16x8*)(W2 + (size_t)(n * 16 + l15) * 2048 + kk + l4 * 8);
            acc[n] = __builtin_amdgcn_mfma_f32_16x16x32_bf16(af, bfr, acc[n], 0, 0, 0);
        }
    }
    if (wave < 4) {
        #pragma unroll
        for (int n = 0; n < 16; ++n)
            #pragma unroll
            for (int r = 0; r < 4; ++r)
                part[wave][l4 * 4 + r][n * 16 + l15] = acc[n][r];
    }
    __syncthreads();
    if (wave >= 4) {
        #pragma unroll
        for (int n = 0; n < 16; ++n)
            #pragma unroll
            for (int r = 0; r < 4; ++r)
                part[wave - 4][l4 * 4 + r][n * 16 + l15] += acc[n][r];
    }
    __syncthreads();

    const int row = tid >> 5, c8 = (tid & 31) * 8;
    f32x4 v0 = *(const f32x4*)&part[0][row][c8];
    f32x4 v1 = *(const f32x4*)&part[0][row][c8 + 4];
    #pragma unroll
    for (int w = 1; w < 4; ++w) {
        v0 += *(const f32x4*)&part[w][row][c8];
        v1 += *(const f32x4*)&part[w][row][c8 + 4];
    }
    float* hrow = h + (size_t)(row0 + row) * 256 + c8;
    v0 += *(const f32x4*)(b2 + c8)     + *(const f32x4*)(hrow);
    v1 += *(const f32x4*)(b2 + c8 + 4) + *(const f32x4*)(hrow + 4);
    float s1 = (v0[0] + v0[1]) + (v0[2] + v0[3]) + (v1[0] + v1[1]) + (v1[2] + v1[3]);
    #pragma unroll
    for (int off = 16; off >= 1; off >>= 1) s1 += __shfl_xor(s1, off);
    const float mu = s1 * (1.0f / 256.0f);
    float s2 = 0.0f;
    #pragma unroll
    for (int q = 0; q < 4; ++q) { float d0 = v0[q] - mu, d1 = v1[q] - mu; s2 += d0 * d0 + d1 * d1; }
    #pragma unroll
    for (int off = 16; off >= 1; off >>= 1) s2 += __shfl_xor(s2, off);
    const float inv = 1.0f / sqrtf(s2 * (1.0f / 256.0f) + 1e-5f);
    short* hbrow = (short*)hb + (size_t)(row0 + row) * 256 + c8;
    const f32x4 gv0 = *(const f32x4*)(g + c8),  gv1 = *(const f32x4*)(g + c8 + 4);
    const f32x4 ev0 = *(const f32x4*)(be + c8), ev1 = *(const f32x4*)(be + c8 + 4);
    f32x4 y0, y1; short4v p0, p1;
    #pragma unroll
    for (int q = 0; q < 4; ++q) {
        y0[q] = (v0[q] - mu) * inv * gv0[q] + ev0[q];
        y1[q] = (v1[q] - mu) * inv * gv1[q] + ev1[q];
        p0[q] = __builtin_bit_cast(short, __float2bfloat16(y0[q]));
        p1[q] = __builtin_bit_cast(short, __float2bfloat16(y1[q]));
    }
    *(f32x4*)(hrow) = y0;  *(f32x4*)(hrow + 4) = y1;
    *(short4v*)(hbrow) = p0;  *(short4v*)(hbrow + 4) = p1;
    bf16x8 hp;
    #pragma unroll
    for (int q = 0; q < 4; ++q) { hp[q] = p0[q]; hp[4 + q] = p1[q]; }
    *(bf16x8*)&hbuf[row][c8] = hp;
    __syncthreads();

    if (!SKIPQKV) {
        // qkv: wave owns output cols [wave*96, wave*96+96); A from hbuf (LDS)
        f32x4 qa[6];
        #pragma unroll
        for (int n = 0; n < 6; ++n) qa[n] = (f32x4)0.0f;
        #pragma unroll
        for (int ks = 0; ks < 8; ++ks) {
            const bf16x8 af = *(const bf16x8*)&hbuf[l15][ks * 32 + l4 * 8];
            #pragma unroll
            for (int n = 0; n < 6; ++n) {
                const bf16x8 bfr = *(const bf16x8*)
                    (Wq + (size_t)(wave * 96 + n * 16 + l15) * 256 + ks * 32 + l4 * 8);
                qa[n] = __builtin_amdgcn_mfma_f32_16x16x32_bf16(af, bfr, qa[n], 0, 0, 0);
            }
        }
        #pragma unroll
        for (int n = 0; n < 6; ++n) {
            const int col = wave * 96 + n * 16 + l15;
            const float bv = bq[col];
            #pragma unroll
            for (int r = 0; r < 4; ++r) {
                const int rowg = row0 + l4 * 4 + r;
                const float v = qa[n][r] + bv;
                if (col >= 512) {
                    const int hh2 = (col >> 5) - 16, d = col & 31;
                    const int bb = rowg >> 10, tt = rowg & 1023;
                    vTb[(((size_t)bb * 8 + hh2) * 32 + d) * 1024 + tt] = __float2bfloat16(v);
                } else {
                    qkvb[(size_t)rowg * 768 + col] = __float2bfloat16(v);
                }
            }
        }
    }
}

// ---------------- gather ----------------
__global__ __launch_bounds__(256) void gather_kernel(
    const float* __restrict__ h, const int* __restrict__ ind, float* __restrict__ out)
{
    int b = blockIdx.x;
    int tid = threadIdx.x;
    out[(b * 2 + 0) * 256 + tid] = h[(b * NTOK + 0) * 256 + tid];
    out[(b * 2 + 1) * 256 + tid] = h[(b * NTOK + ind[b] + 1) * 256 + tid];
}

extern "C" void kernel_launch(void* const* d_in, const int* in_sizes, int n_in,
                              void* d_out, int out_size, void* d_ws, size_t ws_size,
                              hipStream_t stream)
{
    const float* x    = (const float*)d_in[0];
    const int*   ind  = (const int*)d_in[2];
    const float* cls1 = (const float*)d_in[3];
    const float* cls2 = (const float*)d_in[4];
    const float* Wqkv = (const float*)d_in[5];
    const float* bqkv = (const float*)d_in[6];
    const float* Wo   = (const float*)d_in[7];
    const float* bo   = (const float*)d_in[8];
    const float* g1   = (const float*)d_in[9];
    const float* be1  = (const float*)d_in[10];
    const float* W1   = (const float*)d_in[11];
    const float* bf1  = (const float*)d_in[12];
    const float* W2   = (const float*)d_in[13];
    const float* bf2  = (const float*)d_in[14];
    const float* g2   = (const float*)d_in[15];
    const float* be2  = (const float*)d_in[16];
    float* out = (float*)d_out;

    // ---- workspace layout ----
    float* ws   = (float*)d_ws;
    float* h    = ws;                       // 1,048,576 f32
    bf16* hb    = (bf16*)(h + 1048576);     // 1,048,576 bf16
    bf16* qkvb  = hb + 1048576;             // 3,145,728
    bf16* vTb   = qkvb + 3145728;           // 1,048,576
    bf16* ffb   = vTb + 1048576;            // 8,388,608
    bf16* wqkvb = ffb + 8388608;            // 1,179,648
    bf16* wob   = wqkvb + 1179648;          // 393,216
    bf16* w1b   = wob + 393216;             // 3,145,728
    bf16* w2b   = w1b + 3145728;            // 3,145,728

    const int M = BATCH * NTOK;             // 4096

    cast4_kernel<<<7680, 256, 0, stream>>>(Wqkv, wqkvb, Wo, wob, W1, w1b, W2, w2b);
    embed_kernel<<<M, 256, 0, stream>>>(x, cls1, cls2, ind, h, hb);

    // layer-0 qkv (+vT)
    mfma_gemm<2, 4, 0, 0, 0, 1, 1><<<(M / 64) * (768 / 128), 256, 0, stream>>>(
        hb, wqkvb, bqkv, nullptr, nullptr, qkvb, vTb, M, 768, 256);

    for (int l = 0; l < NLAYER; ++l) {
        const bf16*  Wo_l  = wob + (size_t)l * 65536;
        const float* bo_l  = bo + (size_t)l * 256;
        const float* g1_l  = g1 + (size_t)l * 256;
        const float* be1_l = be1 + (size_t)l * 256;
        const bf16*  W1_l  = w1b + (size_t)l * 524288;
        const float* b1_l  = bf1 + (size_t)l * 2048;
        const bf16*  W2_l  = w2b + (size_t)l * 524288;
        const float* b2_l  = bf2 + (size_t)l * 256;
        const float* g2_l  = g2 + (size_t)l * 256;
        const float* be2_l = be2 + (size_t)l * 256;

        // h, hb = LN1(attn(qkvb) @ Wo^T + bo + h)
        attn_wo_ln_kernel<<<BATCH * 64, 512, 0, stream>>>(
            qkvb, vTb, Wo_l, bo_l, g1_l, be1_l, h, hb, ind);
        // ffb = relu(hb @ W1^T + b1)
        mfma_gemm<2, 4, 1, 0, 0, 1, 0><<<(M / 64) * (2048 / 128), 256, 0, stream>>>(
            hb, W1_l, b1_l, nullptr, nullptr, ffb, nullptr, M, 2048, 256);
        // h, hb = LN2(ffb @ W2^T + b2 + h); then qkv for layer l+1
        if (l < NLAYER - 1) {
            w2ln_qkv_kernel<0><<<M / 16, 512, 0, stream>>>(
                ffb, W2_l, b2_l, g2_l, be2_l, h, hb,
                wqkvb + (size_t)(l + 1) * 196608, bqkv + (size_t)(l + 1) * 768, qkvb, vTb);
        } else {
            w2ln_qkv_kernel<1><<<M / 16, 512, 0, stream>>>(
                ffb, W2_l, b2_l, g2_l, be2_l, h, hb,
                nullptr, nullptr, nullptr, nullptr);
        }
    }

    gather_kernel<<<BATCH, 256, 0, stream>>>(h, ind, out);
}

// Round 8
// 619.255 us; speedup vs baseline: 1.1449x; 1.1449x over previous
//
#include <hip/hip_runtime.h>
#include <hip/hip_bf16.h>
#include <math.h>

typedef __hip_bfloat16 bf16;
typedef short bf16x8 __attribute__((ext_vector_type(8)));
typedef short short4v __attribute__((ext_vector_type(4)));
typedef float f32x4 __attribute__((ext_vector_type(4)));

#define D_MODEL 256
#define NTOK 1024
#define SEQ 1022
#define BATCH 4
#define NLAYER 6

// ---- async global->LDS 16B helper ----
__device__ inline void gload_lds16(const void* g, void* l) {
    __builtin_amdgcn_global_load_lds(
        (const __attribute__((address_space(1))) void*)g,
        (__attribute__((address_space(3))) void*)l, 16, 0, 0);
}

// ---------------- merged weight fp32 -> bf16 cast (4 tensors, 1 launch) ----------------
__global__ __launch_bounds__(256) void cast4_kernel(
    const float* __restrict__ s0, bf16* __restrict__ d0,   // 1,179,648
    const float* __restrict__ s1, bf16* __restrict__ d1,   //   393,216
    const float* __restrict__ s2, bf16* __restrict__ d2,   // 3,145,728
    const float* __restrict__ s3, bf16* __restrict__ d3)   // 3,145,728
{
    const int bid = blockIdx.x;
    const float* s; bf16* d; int base;
    if (bid < 1152)      { s = s0; d = d0; base = bid; }
    else if (bid < 1536) { s = s1; d = d1; base = bid - 1152; }
    else if (bid < 4608) { s = s2; d = d2; base = bid - 1536; }
    else                 { s = s3; d = d3; base = bid - 4608; }
    const int i = (base * 256 + threadIdx.x) * 4;
    f32x4 v = *(const f32x4*)(s + i);
    d[i + 0] = __float2bfloat16(v[0]);
    d[i + 1] = __float2bfloat16(v[1]);
    d[i + 2] = __float2bfloat16(v[2]);
    d[i + 3] = __float2bfloat16(v[3]);
}

// ---------------- embed ----------------
__global__ __launch_bounds__(256) void embed_kernel(
    const float* __restrict__ x, const float* __restrict__ cls1,
    const float* __restrict__ cls2, const int* __restrict__ ind,
    float* __restrict__ h, bf16* __restrict__ hb)
{
    int i = blockIdx.x * 256 + threadIdx.x;
    int d = i & 255;
    int pos = (i >> 8) & 1023;
    int b = i >> 18;
    int idx = ind[b];
    float v;
    if (pos == 0) v = cls1[d];
    else if (pos == idx + 1) v = cls2[d];
    else if (pos <= idx) v = x[(b * SEQ + pos - 1) * D_MODEL + d];
    else v = x[(b * SEQ + pos - 2) * D_MODEL + d];
    int p = d >> 1;
    float freq = expf(-(float)p * (logf(10000.0f) / 128.0f));
    float ang = (float)pos * freq;
    v += (d & 1) ? cosf(ang) : sinf(ang);
    h[i] = v;
    hb[i] = __float2bfloat16(v);
}

// ---------------- bf16 MFMA NT GEMM (qkv / W1) ----------------
template<int MR, int NR, int RELU, int HAS_RES, int WF32, int WBF16, int WVT>
__global__ __launch_bounds__(256) void mfma_gemm(
    const bf16* __restrict__ A, const bf16* __restrict__ W,
    const float* __restrict__ bias, const float* __restrict__ R,
    float* __restrict__ Cf, bf16* __restrict__ Cb, bf16* __restrict__ vTb,
    int M, int N, int K)
{
    constexpr int BM = MR * 32, BN = NR * 32;
    constexpr int ACH = BM * 4;
    constexpr int BCH = BN * 4;
    __shared__ bf16 As[2][BM * 32];
    __shared__ bf16 Bs[2][BN * 32];
    const int ntile = N / BN;
    const int bx = blockIdx.x % ntile, by = blockIdx.x / ntile;
    const int row0 = by * BM, col0 = bx * BN;
    const int tid = threadIdx.x, lane = tid & 63, wave = tid >> 6;
    const int wr = wave >> 1, wc = wave & 1;
    const int l15 = lane & 15, l4 = lane >> 4;

    f32x4 acc[MR][NR];
    #pragma unroll
    for (int m = 0; m < MR; ++m)
        #pragma unroll
        for (int n = 0; n < NR; ++n) acc[m][n] = (f32x4)0.0f;

    const int nk = K / 32;

    auto stage = [&](int buf, int t) {
        const int k0 = t * 32;
        #pragma unroll
        for (int p = 0; p < ACH / 256; ++p) {
            const int cbase = p * 256 + wave * 64;
            const int chunk = cbase + lane;
            const int r = chunk >> 2, c = chunk & 3;
            gload_lds16(A + (size_t)(row0 + r) * K + k0 + c * 8, &As[buf][cbase * 8]);
        }
        #pragma unroll
        for (int p = 0; p < BCH / 256; ++p) {
            const int cbase = p * 256 + wave * 64;
            const int chunk = cbase + lane;
            const int r = chunk >> 2, c = chunk & 3;
            gload_lds16(W + (size_t)(col0 + r) * K + k0 + c * 8, &Bs[buf][cbase * 8]);
        }
    };

    stage(0, 0);
    __syncthreads();
    int cur = 0;
    for (int t = 0; t < nk; ++t) {
        if (t + 1 < nk) stage(cur ^ 1, t + 1);
        bf16x8 af[MR], bfr[NR];
        #pragma unroll
        for (int m = 0; m < MR; ++m)
            af[m] = *(const bf16x8*)&As[cur][(wr * MR * 16 + m * 16 + l15) * 32 + l4 * 8];
        #pragma unroll
        for (int n = 0; n < NR; ++n)
            bfr[n] = *(const bf16x8*)&Bs[cur][(wc * NR * 16 + n * 16 + l15) * 32 + l4 * 8];
        #pragma unroll
        for (int m = 0; m < MR; ++m)
            #pragma unroll
            for (int n = 0; n < NR; ++n)
                acc[m][n] = __builtin_amdgcn_mfma_f32_16x16x32_bf16(af[m], bfr[n], acc[m][n], 0, 0, 0);
        __syncthreads();
        cur ^= 1;
    }

    #pragma unroll
    for (int m = 0; m < MR; ++m) {
        #pragma unroll
        for (int n = 0; n < NR; ++n) {
            const int col = col0 + wc * NR * 16 + n * 16 + l15;
            const float bv = bias[col];
            #pragma unroll
            for (int r = 0; r < 4; ++r) {
                const int row = row0 + wr * MR * 16 + m * 16 + l4 * 4 + r;
                float v = acc[m][n][r] + bv;
                if (HAS_RES) v += R[(size_t)row * N + col];
                if (RELU) v = fmaxf(v, 0.0f);
                if (WF32) Cf[(size_t)row * N + col] = v;
                if (WBF16) {
                    if (WVT && col >= 512) {
                        const int hh = (col >> 5) - 16, d = col & 31;
                        const int bb = row >> 10, tt = row & 1023;
                        vTb[(((size_t)bb * 8 + hh) * 32 + d) * 1024 + tt] = __float2bfloat16(v);
                    } else {
                        Cb[(size_t)row * N + col] = __float2bfloat16(v);
                    }
                }
            }
        }
    }
}

// ---------------- fused N=256 GEMM + bias + residual + LayerNorm (8-wave split-K) ----------------
// grid: M/16 blocks, 512 threads = 8 waves (2/SIMD). Block owns 16 rows x 256 cols.
// Waves split K 8-ways; A/B fragments straight from global; two-phase LDS reduce;
// LN fused in-register. h read (residual) + overwritten; hb bf16 copy.
template<int K>
__global__ __launch_bounds__(512) void gemm256_ln8_kernel(
    const bf16* __restrict__ A, const bf16* __restrict__ W,
    const float* __restrict__ bias, const float* __restrict__ g,
    const float* __restrict__ be, float* __restrict__ h, bf16* __restrict__ hb)
{
    constexpr int KW = K / 8;
    constexpr int NSTEP = KW / 32;
    __shared__ float part[4][16][260];
    const int tid = threadIdx.x, lane = tid & 63, wave = tid >> 6;
    const int l15 = lane & 15, l4 = lane >> 4;
    const int row0 = blockIdx.x * 16;

    f32x4 acc[16];
    #pragma unroll
    for (int n = 0; n < 16; ++n) acc[n] = (f32x4)0.0f;
    #pragma unroll
    for (int s = 0; s < NSTEP; ++s) {
        const int kk = wave * KW + s * 32;
        const bf16x8 af = *(const bf16x8*)(A + (size_t)(row0 + l15) * K + kk + l4 * 8);
        #pragma unroll
        for (int n = 0; n < 16; ++n) {
            const bf16x8 bfr = *(const bf16x8*)(W + (size_t)(n * 16 + l15) * K + kk + l4 * 8);
            acc[n] = __builtin_amdgcn_mfma_f32_16x16x32_bf16(af, bfr, acc[n], 0, 0, 0);
        }
    }
    if (wave < 4) {
        #pragma unroll
        for (int n = 0; n < 16; ++n)
            #pragma unroll
            for (int r = 0; r < 4; ++r)
                part[wave][l4 * 4 + r][n * 16 + l15] = acc[n][r];
    }
    __syncthreads();
    if (wave >= 4) {
        #pragma unroll
        for (int n = 0; n < 16; ++n)
            #pragma unroll
            for (int r = 0; r < 4; ++r)
                part[wave - 4][l4 * 4 + r][n * 16 + l15] += acc[n][r];
    }
    __syncthreads();

    // epilogue: row = tid>>5 (16 rows x 32 threads), 8 cols/thread
    const int row = tid >> 5, c8 = (tid & 31) * 8;
    f32x4 v0 = *(const f32x4*)&part[0][row][c8];
    f32x4 v1 = *(const f32x4*)&part[0][row][c8 + 4];
    #pragma unroll
    for (int w = 1; w < 4; ++w) {
        v0 += *(const f32x4*)&part[w][row][c8];
        v1 += *(const f32x4*)&part[w][row][c8 + 4];
    }
    float* hrow = h + (size_t)(row0 + row) * 256 + c8;
    v0 += *(const f32x4*)(bias + c8)     + *(const f32x4*)(hrow);
    v1 += *(const f32x4*)(bias + c8 + 4) + *(const f32x4*)(hrow + 4);
    float s1 = (v0[0] + v0[1]) + (v0[2] + v0[3]) + (v1[0] + v1[1]) + (v1[2] + v1[3]);
    #pragma unroll
    for (int off = 16; off >= 1; off >>= 1) s1 += __shfl_xor(s1, off);
    const float mu = s1 * (1.0f / 256.0f);
    float s2 = 0.0f;
    #pragma unroll
    for (int q = 0; q < 4; ++q) { float d0 = v0[q] - mu, d1 = v1[q] - mu; s2 += d0 * d0 + d1 * d1; }
    #pragma unroll
    for (int off = 16; off >= 1; off >>= 1) s2 += __shfl_xor(s2, off);
    const float inv = 1.0f / sqrtf(s2 * (1.0f / 256.0f) + 1e-5f);
    short* hbrow = (short*)hb + (size_t)(row0 + row) * 256 + c8;
    const f32x4 gv0 = *(const f32x4*)(g + c8),  gv1 = *(const f32x4*)(g + c8 + 4);
    const f32x4 ev0 = *(const f32x4*)(be + c8), ev1 = *(const f32x4*)(be + c8 + 4);
    f32x4 y0, y1; short4v p0, p1;
    #pragma unroll
    for (int q = 0; q < 4; ++q) {
        y0[q] = (v0[q] - mu) * inv * gv0[q] + ev0[q];
        y1[q] = (v1[q] - mu) * inv * gv1[q] + ev1[q];
        p0[q] = __builtin_bit_cast(short, __float2bfloat16(y0[q]));
        p1[q] = __builtin_bit_cast(short, __float2bfloat16(y1[q]));
    }
    *(f32x4*)(hrow) = y0;  *(f32x4*)(hrow + 4) = y1;
    *(short4v*)(hbrow) = p0;  *(short4v*)(hbrow + 4) = p1;
}

// ---------------- barrier-free MFMA flash attention (R5-proven) ----------------
__global__ __launch_bounds__(256) void attn_mfma_kernel(
    const bf16* __restrict__ qkvb, const bf16* __restrict__ vT,
    bf16* __restrict__ att, const int* __restrict__ ind)
{
    __shared__ bf16 Ps[4][16][72];
    const int qt = blockIdx.x & 15;
    const int hh = (blockIdx.x >> 4) & 7;
    const int b  = blockIdx.x >> 7;
    const int idx = ind[b];
    const int segEnd = NTOK - ind[4 + b];
    const int tid = threadIdx.x, lane = tid & 63, wave = tid >> 6;
    const int l15 = lane & 15, l4 = lane >> 4;
    const int q0 = qt * 64 + wave * 16;
    const size_t tokbase = (size_t)b * NTOK;
    const bf16* vTh = vT + (((size_t)b * 8 + hh) * 32) * 1024;
    const float scale = 0.17677669529663687f;

    const bf16x8 qfrag = *(const bf16x8*)(qkvb + (tokbase + q0 + l15) * 768 + hh * 32 + l4 * 8);

    f32x4 acc_o[2];
    acc_o[0] = (f32x4)0.0f; acc_o[1] = (f32x4)0.0f;
    float mrun[4], lrun[4];
    bool v1q[4], v2q[4];
    #pragma unroll
    for (int r = 0; r < 4; ++r) {
        mrun[r] = -1e30f; lrun[r] = 0.0f;
        const int qg = q0 + l4 * 4 + r;
        v1q[r] = (qg <= idx);
        v2q[r] = (qg > idx) && (qg < segEnd);
    }

    const int kbeg = (q0 <= idx) ? 0 : (idx + 1);
    const int kend = (q0 + 15 > idx) ? segEnd : (idx + 1);

    for (int k0 = (kbeg & ~63); k0 < kend; k0 += 64) {
        f32x4 sc[4];
        #pragma unroll
        for (int kt = 0; kt < 4; ++kt) {
            const bf16x8 kf = *(const bf16x8*)
                (qkvb + (tokbase + k0 + kt * 16 + l15) * 768 + 256 + hh * 32 + l4 * 8);
            sc[kt] = __builtin_amdgcn_mfma_f32_16x16x32_bf16(qfrag, kf, (f32x4)0.0f, 0, 0, 0);
        }
        float mloc[4] = {-1e30f, -1e30f, -1e30f, -1e30f};
        #pragma unroll
        for (int kt = 0; kt < 4; ++kt) {
            const int k = k0 + kt * 16 + l15;
            const bool v1k = (k <= idx);
            const bool v2k = (k > idx) && (k < segEnd);
            #pragma unroll
            for (int r = 0; r < 4; ++r) {
                const bool ok = (v1q[r] && v1k) || (v2q[r] && v2k);
                const float s = ok ? sc[kt][r] * scale : -1e30f;
                sc[kt][r] = s;
                mloc[r] = fmaxf(mloc[r], s);
            }
        }
        #pragma unroll
        for (int r = 0; r < 4; ++r) {
            mloc[r] = fmaxf(mloc[r], __shfl_xor(mloc[r], 1));
            mloc[r] = fmaxf(mloc[r], __shfl_xor(mloc[r], 2));
            mloc[r] = fmaxf(mloc[r], __shfl_xor(mloc[r], 4));
            mloc[r] = fmaxf(mloc[r], __shfl_xor(mloc[r], 8));
            const float mnew = fmaxf(mrun[r], mloc[r]);
            const float c = __expf(mrun[r] - mnew);
            mrun[r] = mnew;
            mloc[r] = c;            // corr
        }
        float psum[4] = {0.0f, 0.0f, 0.0f, 0.0f};
        #pragma unroll
        for (int kt = 0; kt < 4; ++kt) {
            #pragma unroll
            for (int r = 0; r < 4; ++r) {
                const float s = sc[kt][r];
                const float p = (s > -5e29f) ? __expf(s - mrun[r]) : 0.0f;
                psum[r] += p;
                Ps[wave][l4 * 4 + r][kt * 16 + l15] = __float2bfloat16(p);
            }
        }
        #pragma unroll
        for (int r = 0; r < 4; ++r) {
            float ps = psum[r];
            ps += __shfl_xor(ps, 1); ps += __shfl_xor(ps, 2);
            ps += __shfl_xor(ps, 4); ps += __shfl_xor(ps, 8);
            lrun[r] = lrun[r] * mloc[r] + ps;
            acc_o[0][r] *= mloc[r];
            acc_o[1][r] *= mloc[r];
        }
        #pragma unroll
        for (int ks = 0; ks < 2; ++ks) {
            const bf16x8 pa = *(const bf16x8*)&Ps[wave][l15][ks * 32 + l4 * 8];
            #pragma unroll
            for (int dt = 0; dt < 2; ++dt) {
                const bf16x8 vb = *(const bf16x8*)
                    (vTh + (size_t)(dt * 16 + l15) * 1024 + k0 + ks * 32 + l4 * 8);
                acc_o[dt] = __builtin_amdgcn_mfma_f32_16x16x32_bf16(pa, vb, acc_o[dt], 0, 0, 0);
            }
        }
    }

    #pragma unroll
    for (int r = 0; r < 4; ++r) {
        const float invl = (lrun[r] > 0.0f) ? (1.0f / lrun[r]) : 0.0f;
        const int qg = q0 + l4 * 4 + r;
        bf16* op = att + (tokbase + qg) * 256 + hh * 32 + l15;
        op[0]  = __float2bfloat16(acc_o[0][r] * invl);
        op[16] = __float2bfloat16(acc_o[1][r] * invl);
    }
}

// ---------------- gather ----------------
__global__ __launch_bounds__(256) void gather_kernel(
    const float* __restrict__ h, const int* __restrict__ ind, float* __restrict__ out)
{
    int b = blockIdx.x;
    int tid = threadIdx.x;
    out[(b * 2 + 0) * 256 + tid] = h[(b * NTOK + 0) * 256 + tid];
    out[(b * 2 + 1) * 256 + tid] = h[(b * NTOK + ind[b] + 1) * 256 + tid];
}

extern "C" void kernel_launch(void* const* d_in, const int* in_sizes, int n_in,
                              void* d_out, int out_size, void* d_ws, size_t ws_size,
                              hipStream_t stream)
{
    const float* x    = (const float*)d_in[0];
    const int*   ind  = (const int*)d_in[2];
    const float* cls1 = (const float*)d_in[3];
    const float* cls2 = (const float*)d_in[4];
    const float* Wqkv = (const float*)d_in[5];
    const float* bqkv = (const float*)d_in[6];
    const float* Wo   = (const float*)d_in[7];
    const float* bo   = (const float*)d_in[8];
    const float* g1   = (const float*)d_in[9];
    const float* be1  = (const float*)d_in[10];
    const float* W1   = (const float*)d_in[11];
    const float* bf1  = (const float*)d_in[12];
    const float* W2   = (const float*)d_in[13];
    const float* bf2  = (const float*)d_in[14];
    const float* g2   = (const float*)d_in[15];
    const float* be2  = (const float*)d_in[16];
    float* out = (float*)d_out;

    // ---- workspace layout ----
    float* ws   = (float*)d_ws;
    float* h    = ws;                       // 1,048,576 f32
    bf16* hb    = (bf16*)(h + 1048576);     // 1,048,576 bf16
    bf16* qkvb  = hb + 1048576;             // 3,145,728
    bf16* vTb   = qkvb + 3145728;           // 1,048,576
    bf16* attb  = vTb + 1048576;            // 1,048,576
    bf16* ffb   = attb + 1048576;           // 8,388,608
    bf16* wqkvb = ffb + 8388608;            // 1,179,648
    bf16* wob   = wqkvb + 1179648;          // 393,216
    bf16* w1b   = wob + 393216;             // 3,145,728
    bf16* w2b   = w1b + 3145728;            // 3,145,728

    const int M = BATCH * NTOK;             // 4096

    cast4_kernel<<<7680, 256, 0, stream>>>(Wqkv, wqkvb, Wo, wob, W1, w1b, W2, w2b);
    embed_kernel<<<M, 256, 0, stream>>>(x, cls1, cls2, ind, h, hb);

    for (int l = 0; l < NLAYER; ++l) {
        const bf16*  Wqkv_l = wqkvb + (size_t)l * 196608;
        const float* bqkv_l = bqkv + (size_t)l * 768;
        const bf16*  Wo_l   = wob + (size_t)l * 65536;
        const float* bo_l   = bo + (size_t)l * 256;
        const float* g1_l   = g1 + (size_t)l * 256;
        const float* be1_l  = be1 + (size_t)l * 256;
        const bf16*  W1_l   = w1b + (size_t)l * 524288;
        const float* b1_l   = bf1 + (size_t)l * 2048;
        const bf16*  W2_l   = w2b + (size_t)l * 524288;
        const float* b2_l   = bf2 + (size_t)l * 256;
        const float* g2_l   = g2 + (size_t)l * 256;
        const float* be2_l  = be2 + (size_t)l * 256;

        // qkvb = hb @ Wqkv^T + bqkv ; V-part redirected to vT layout
        mfma_gemm<2, 4, 0, 0, 0, 1, 1><<<(M / 64) * (768 / 128), 256, 0, stream>>>(
            hb, Wqkv_l, bqkv_l, nullptr, nullptr, qkvb, vTb, M, 768, 256);
        // attb = softmax(qk^T + seg-bias) v   (barrier-free)
        attn_mfma_kernel<<<BATCH * 8 * 16, 256, 0, stream>>>(qkvb, vTb, attb, ind);
        // h, hb = LN1(attb @ Wo^T + bo + h)   (8-wave split-K)
        gemm256_ln8_kernel<256><<<M / 16, 512, 0, stream>>>(
            attb, Wo_l, bo_l, g1_l, be1_l, h, hb);
        // ffb = relu(hb @ W1^T + b1)
        mfma_gemm<2, 4, 1, 0, 0, 1, 0><<<(M / 64) * (2048 / 128), 256, 0, stream>>>(
            hb, W1_l, b1_l, nullptr, nullptr, ffb, nullptr, M, 2048, 256);
        // h, hb = LN2(ffb @ W2^T + b2 + h)    (8-wave split-K)
        gemm256_ln8_kernel<2048><<<M / 16, 512, 0, stream>>>(
            ffb, W2_l, b2_l, g2_l, be2_l, h, hb);
    }

    gather_kernel<<<BATCH, 256, 0, stream>>>(h, ind, out);
}

// Round 9
// 546.894 us; speedup vs baseline: 1.2964x; 1.1323x over previous
//
#include <hip/hip_runtime.h>
#include <hip/hip_bf16.h>
#include <math.h>

typedef __hip_bfloat16 bf16;
typedef short bf16x8 __attribute__((ext_vector_type(8)));
typedef short short4v __attribute__((ext_vector_type(4)));
typedef float f32x4 __attribute__((ext_vector_type(4)));

#define D_MODEL 256
#define NTOK 1024
#define SEQ 1022
#define BATCH 4
#define NLAYER 6

// ---- async global->LDS 16B helper ----
__device__ inline void gload_lds16(const void* g, void* l) {
    __builtin_amdgcn_global_load_lds(
        (const __attribute__((address_space(1))) void*)g,
        (__attribute__((address_space(3))) void*)l, 16, 0, 0);
}

// ---------------- merged weight fp32 -> bf16 cast (4 tensors, 1 launch) ----------------
__global__ __launch_bounds__(256) void cast4_kernel(
    const float* __restrict__ s0, bf16* __restrict__ d0,   // 1,179,648
    const float* __restrict__ s1, bf16* __restrict__ d1,   //   393,216
    const float* __restrict__ s2, bf16* __restrict__ d2,   // 3,145,728
    const float* __restrict__ s3, bf16* __restrict__ d3)   // 3,145,728
{
    const int bid = blockIdx.x;
    const float* s; bf16* d; int base;
    if (bid < 1152)      { s = s0; d = d0; base = bid; }
    else if (bid < 1536) { s = s1; d = d1; base = bid - 1152; }
    else if (bid < 4608) { s = s2; d = d2; base = bid - 1536; }
    else                 { s = s3; d = d3; base = bid - 4608; }
    const int i = (base * 256 + threadIdx.x) * 4;
    f32x4 v = *(const f32x4*)(s + i);
    d[i + 0] = __float2bfloat16(v[0]);
    d[i + 1] = __float2bfloat16(v[1]);
    d[i + 2] = __float2bfloat16(v[2]);
    d[i + 3] = __float2bfloat16(v[3]);
}

// ---------------- embed ----------------
__global__ __launch_bounds__(256) void embed_kernel(
    const float* __restrict__ x, const float* __restrict__ cls1,
    const float* __restrict__ cls2, const int* __restrict__ ind,
    float* __restrict__ h, bf16* __restrict__ hb)
{
    int i = blockIdx.x * 256 + threadIdx.x;
    int d = i & 255;
    int pos = (i >> 8) & 1023;
    int b = i >> 18;
    int idx = ind[b];
    float v;
    if (pos == 0) v = cls1[d];
    else if (pos == idx + 1) v = cls2[d];
    else if (pos <= idx) v = x[(b * SEQ + pos - 1) * D_MODEL + d];
    else v = x[(b * SEQ + pos - 2) * D_MODEL + d];
    int p = d >> 1;
    float freq = expf(-(float)p * (logf(10000.0f) / 128.0f));
    float ang = (float)pos * freq;
    v += (d & 1) ? cosf(ang) : sinf(ang);
    h[i] = v;
    hb[i] = __float2bfloat16(v);
}

// ---------------- bf16 MFMA NT GEMM (qkv / W1 / W2) ----------------
template<int MR, int NR, int RELU, int HAS_RES, int WF32, int WBF16, int WVT>
__global__ __launch_bounds__(256) void mfma_gemm(
    const bf16* __restrict__ A, const bf16* __restrict__ W,
    const float* __restrict__ bias, const float* __restrict__ R,
    float* __restrict__ Cf, bf16* __restrict__ Cb, bf16* __restrict__ vTb,
    int M, int N, int K)
{
    constexpr int BM = MR * 32, BN = NR * 32;
    constexpr int ACH = BM * 4;
    constexpr int BCH = BN * 4;
    __shared__ bf16 As[2][BM * 32];
    __shared__ bf16 Bs[2][BN * 32];
    const int ntile = N / BN;
    const int bx = blockIdx.x % ntile, by = blockIdx.x / ntile;
    const int row0 = by * BM, col0 = bx * BN;
    const int tid = threadIdx.x, lane = tid & 63, wave = tid >> 6;
    const int wr = wave >> 1, wc = wave & 1;
    const int l15 = lane & 15, l4 = lane >> 4;

    f32x4 acc[MR][NR];
    #pragma unroll
    for (int m = 0; m < MR; ++m)
        #pragma unroll
        for (int n = 0; n < NR; ++n) acc[m][n] = (f32x4)0.0f;

    const int nk = K / 32;

    auto stage = [&](int buf, int t) {
        const int k0 = t * 32;
        #pragma unroll
        for (int p = 0; p < ACH / 256; ++p) {
            const int cbase = p * 256 + wave * 64;
            const int chunk = cbase + lane;
            const int r = chunk >> 2, c = chunk & 3;
            gload_lds16(A + (size_t)(row0 + r) * K + k0 + c * 8, &As[buf][cbase * 8]);
        }
        #pragma unroll
        for (int p = 0; p < BCH / 256; ++p) {
            const int cbase = p * 256 + wave * 64;
            const int chunk = cbase + lane;
            const int r = chunk >> 2, c = chunk & 3;
            gload_lds16(W + (size_t)(col0 + r) * K + k0 + c * 8, &Bs[buf][cbase * 8]);
        }
    };

    stage(0, 0);
    __syncthreads();
    int cur = 0;
    for (int t = 0; t < nk; ++t) {
        if (t + 1 < nk) stage(cur ^ 1, t + 1);
        bf16x8 af[MR], bfr[NR];
        #pragma unroll
        for (int m = 0; m < MR; ++m)
            af[m] = *(const bf16x8*)&As[cur][(wr * MR * 16 + m * 16 + l15) * 32 + l4 * 8];
        #pragma unroll
        for (int n = 0; n < NR; ++n)
            bfr[n] = *(const bf16x8*)&Bs[cur][(wc * NR * 16 + n * 16 + l15) * 32 + l4 * 8];
        #pragma unroll
        for (int m = 0; m < MR; ++m)
            #pragma unroll
            for (int n = 0; n < NR; ++n)
                acc[m][n] = __builtin_amdgcn_mfma_f32_16x16x32_bf16(af[m], bfr[n], acc[m][n], 0, 0, 0);
        __syncthreads();
        cur ^= 1;
    }

    #pragma unroll
    for (int m = 0; m < MR; ++m) {
        #pragma unroll
        for (int n = 0; n < NR; ++n) {
            const int col = col0 + wc * NR * 16 + n * 16 + l15;
            const float bv = bias[col];
            #pragma unroll
            for (int r = 0; r < 4; ++r) {
                const int row = row0 + wr * MR * 16 + m * 16 + l4 * 4 + r;
                float v = acc[m][n][r] + bv;
                if (HAS_RES) v += R[(size_t)row * N + col];
                if (RELU) v = fmaxf(v, 0.0f);
                if (WF32) Cf[(size_t)row * N + col] = v;
                if (WBF16) {
                    if (WVT && col >= 512) {
                        const int hh = (col >> 5) - 16, d = col & 31;
                        const int bb = row >> 10, tt = row & 1023;
                        vTb[(((size_t)bb * 8 + hh) * 32 + d) * 1024 + tt] = __float2bfloat16(v);
                    } else {
                        Cb[(size_t)row * N + col] = __float2bfloat16(v);
                    }
                }
            }
        }
    }
}

// ---------------- fused N=256 GEMM + bias + residual + LayerNorm (8-wave split-K, Wo only) ----------------
template<int K>
__global__ __launch_bounds__(512) void gemm256_ln8_kernel(
    const bf16* __restrict__ A, const bf16* __restrict__ W,
    const float* __restrict__ bias, const float* __restrict__ g,
    const float* __restrict__ be, float* __restrict__ h, bf16* __restrict__ hb)
{
    constexpr int KW = K / 8;
    constexpr int NSTEP = KW / 32;
    __shared__ float part[4][16][260];
    const int tid = threadIdx.x, lane = tid & 63, wave = tid >> 6;
    const int l15 = lane & 15, l4 = lane >> 4;
    const int row0 = blockIdx.x * 16;

    f32x4 acc[16];
    #pragma unroll
    for (int n = 0; n < 16; ++n) acc[n] = (f32x4)0.0f;
    #pragma unroll
    for (int s = 0; s < NSTEP; ++s) {
        const int kk = wave * KW + s * 32;
        const bf16x8 af = *(const bf16x8*)(A + (size_t)(row0 + l15) * K + kk + l4 * 8);
        #pragma unroll
        for (int n = 0; n < 16; ++n) {
            const bf16x8 bfr = *(const bf16x8*)(W + (size_t)(n * 16 + l15) * K + kk + l4 * 8);
            acc[n] = __builtin_amdgcn_mfma_f32_16x16x32_bf16(af, bfr, acc[n], 0, 0, 0);
        }
    }
    if (wave < 4) {
        #pragma unroll
        for (int n = 0; n < 16; ++n)
            #pragma unroll
            for (int r = 0; r < 4; ++r)
                part[wave][l4 * 4 + r][n * 16 + l15] = acc[n][r];
    }
    __syncthreads();
    if (wave >= 4) {
        #pragma unroll
        for (int n = 0; n < 16; ++n)
            #pragma unroll
            for (int r = 0; r < 4; ++r)
                part[wave - 4][l4 * 4 + r][n * 16 + l15] += acc[n][r];
    }
    __syncthreads();

    const int row = tid >> 5, c8 = (tid & 31) * 8;
    f32x4 v0 = *(const f32x4*)&part[0][row][c8];
    f32x4 v1 = *(const f32x4*)&part[0][row][c8 + 4];
    #pragma unroll
    for (int w = 1; w < 4; ++w) {
        v0 += *(const f32x4*)&part[w][row][c8];
        v1 += *(const f32x4*)&part[w][row][c8 + 4];
    }
    float* hrow = h + (size_t)(row0 + row) * 256 + c8;
    v0 += *(const f32x4*)(bias + c8)     + *(const f32x4*)(hrow);
    v1 += *(const f32x4*)(bias + c8 + 4) + *(const f32x4*)(hrow + 4);
    float s1 = (v0[0] + v0[1]) + (v0[2] + v0[3]) + (v1[0] + v1[1]) + (v1[2] + v1[3]);
    #pragma unroll
    for (int off = 16; off >= 1; off >>= 1) s1 += __shfl_xor(s1, off);
    const float mu = s1 * (1.0f / 256.0f);
    float s2 = 0.0f;
    #pragma unroll
    for (int q = 0; q < 4; ++q) { float d0 = v0[q] - mu, d1 = v1[q] - mu; s2 += d0 * d0 + d1 * d1; }
    #pragma unroll
    for (int off = 16; off >= 1; off >>= 1) s2 += __shfl_xor(s2, off);
    const float inv = 1.0f / sqrtf(s2 * (1.0f / 256.0f) + 1e-5f);
    short* hbrow = (short*)hb + (size_t)(row0 + row) * 256 + c8;
    const f32x4 gv0 = *(const f32x4*)(g + c8),  gv1 = *(const f32x4*)(g + c8 + 4);
    const f32x4 ev0 = *(const f32x4*)(be + c8), ev1 = *(const f32x4*)(be + c8 + 4);
    f32x4 y0, y1; short4v p0, p1;
    #pragma unroll
    for (int q = 0; q < 4; ++q) {
        y0[q] = (v0[q] - mu) * inv * gv0[q] + ev0[q];
        y1[q] = (v1[q] - mu) * inv * gv1[q] + ev1[q];
        p0[q] = __builtin_bit_cast(short, __float2bfloat16(y0[q]));
        p1[q] = __builtin_bit_cast(short, __float2bfloat16(y1[q]));
    }
    *(f32x4*)(hrow) = y0;  *(f32x4*)(hrow + 4) = y1;
    *(short4v*)(hbrow) = p0;  *(short4v*)(hbrow + 4) = p1;
}

// ---------------- LayerNorm: one wave per row ----------------
__global__ __launch_bounds__(256) void ln_kernel(
    const float* __restrict__ X, const float* __restrict__ g,
    const float* __restrict__ bb, float* __restrict__ Y, bf16* __restrict__ Yb)
{
    const int row = blockIdx.x * 4 + (threadIdx.x >> 6);
    const int lane = threadIdx.x & 63;
    const f32x4 xv = *(const f32x4*)(X + (size_t)row * 256 + lane * 4);
    float s = (xv[0] + xv[1]) + (xv[2] + xv[3]);
    #pragma unroll
    for (int off = 32; off >= 1; off >>= 1) s += __shfl_xor(s, off);
    const float mu = s * (1.0f / 256.0f);
    f32x4 dv;
    float s2 = 0.0f;
    #pragma unroll
    for (int e = 0; e < 4; ++e) { dv[e] = xv[e] - mu; s2 += dv[e] * dv[e]; }
    #pragma unroll
    for (int off = 32; off >= 1; off >>= 1) s2 += __shfl_xor(s2, off);
    const float inv = 1.0f / sqrtf(s2 * (1.0f / 256.0f) + 1e-5f);
    const f32x4 gv = *(const f32x4*)(g + lane * 4);
    const f32x4 bv = *(const f32x4*)(bb + lane * 4);
    f32x4 y;
    short4v pk;
    #pragma unroll
    for (int e = 0; e < 4; ++e) {
        y[e] = dv[e] * inv * gv[e] + bv[e];
        pk[e] = __builtin_bit_cast(short, __float2bfloat16(y[e]));
    }
    *(f32x4*)(Y + (size_t)row * 256 + lane * 4) = y;
    *(short4v*)((short*)Yb + (size_t)row * 256 + lane * 4) = pk;
}

// ---------------- barrier-free MFMA flash attention ----------------
__global__ __launch_bounds__(256) void attn_mfma_kernel(
    const bf16* __restrict__ qkvb, const bf16* __restrict__ vT,
    bf16* __restrict__ att, const int* __restrict__ ind)
{
    __shared__ bf16 Ps[4][16][72];
    const int qt = blockIdx.x & 15;
    const int hh = (blockIdx.x >> 4) & 7;
    const int b  = blockIdx.x >> 7;
    const int idx = ind[b];
    const int segEnd = NTOK - ind[4 + b];
    const int tid = threadIdx.x, lane = tid & 63, wave = tid >> 6;
    const int l15 = lane & 15, l4 = lane >> 4;
    const int q0 = qt * 64 + wave * 16;
    const size_t tokbase = (size_t)b * NTOK;
    const bf16* vTh = vT + (((size_t)b * 8 + hh) * 32) * 1024;
    const float scale = 0.17677669529663687f;

    const bf16x8 qfrag = *(const bf16x8*)(qkvb + (tokbase + q0 + l15) * 768 + hh * 32 + l4 * 8);

    f32x4 acc_o[2];
    acc_o[0] = (f32x4)0.0f; acc_o[1] = (f32x4)0.0f;
    float mrun[4], lrun[4];
    bool v1q[4], v2q[4];
    #pragma unroll
    for (int r = 0; r < 4; ++r) {
        mrun[r] = -1e30f; lrun[r] = 0.0f;
        const int qg = q0 + l4 * 4 + r;
        v1q[r] = (qg <= idx);
        v2q[r] = (qg > idx) && (qg < segEnd);
    }

    const int kbeg = (q0 <= idx) ? 0 : (idx + 1);
    const int kend = (q0 + 15 > idx) ? segEnd : (idx + 1);

    for (int k0 = (kbeg & ~63); k0 < kend; k0 += 64) {
        f32x4 sc[4];
        #pragma unroll
        for (int kt = 0; kt < 4; ++kt) {
            const bf16x8 kf = *(const bf16x8*)
                (qkvb + (tokbase + k0 + kt * 16 + l15) * 768 + 256 + hh * 32 + l4 * 8);
            sc[kt] = __builtin_amdgcn_mfma_f32_16x16x32_bf16(qfrag, kf, (f32x4)0.0f, 0, 0, 0);
        }
        float mloc[4] = {-1e30f, -1e30f, -1e30f, -1e30f};
        #pragma unroll
        for (int kt = 0; kt < 4; ++kt) {
            const int k = k0 + kt * 16 + l15;
            const bool v1k = (k <= idx);
            const bool v2k = (k > idx) && (k < segEnd);
            #pragma unroll
            for (int r = 0; r < 4; ++r) {
                const bool ok = (v1q[r] && v1k) || (v2q[r] && v2k);
                const float s = ok ? sc[kt][r] * scale : -1e30f;
                sc[kt][r] = s;
                mloc[r] = fmaxf(mloc[r], s);
            }
        }
        #pragma unroll
        for (int r = 0; r < 4; ++r) {
            mloc[r] = fmaxf(mloc[r], __shfl_xor(mloc[r], 1));
            mloc[r] = fmaxf(mloc[r], __shfl_xor(mloc[r], 2));
            mloc[r] = fmaxf(mloc[r], __shfl_xor(mloc[r], 4));
            mloc[r] = fmaxf(mloc[r], __shfl_xor(mloc[r], 8));
            const float mnew = fmaxf(mrun[r], mloc[r]);
            const float c = __expf(mrun[r] - mnew);
            mrun[r] = mnew;
            mloc[r] = c;            // corr
        }
        float psum[4] = {0.0f, 0.0f, 0.0f, 0.0f};
        #pragma unroll
        for (int kt = 0; kt < 4; ++kt) {
            #pragma unroll
            for (int r = 0; r < 4; ++r) {
                const float s = sc[kt][r];
                const float p = (s > -5e29f) ? __expf(s - mrun[r]) : 0.0f;
                psum[r] += p;
                Ps[wave][l4 * 4 + r][kt * 16 + l15] = __float2bfloat16(p);
            }
        }
        #pragma unroll
        for (int r = 0; r < 4; ++r) {
            float ps = psum[r];
            ps += __shfl_xor(ps, 1); ps += __shfl_xor(ps, 2);
            ps += __shfl_xor(ps, 4); ps += __shfl_xor(ps, 8);
            lrun[r] = lrun[r] * mloc[r] + ps;
            acc_o[0][r] *= mloc[r];
            acc_o[1][r] *= mloc[r];
        }
        #pragma unroll
        for (int ks = 0; ks < 2; ++ks) {
            const bf16x8 pa = *(const bf16x8*)&Ps[wave][l15][ks * 32 + l4 * 8];
            #pragma unroll
            for (int dt = 0; dt < 2; ++dt) {
                const bf16x8 vb = *(const bf16x8*)
                    (vTh + (size_t)(dt * 16 + l15) * 1024 + k0 + ks * 32 + l4 * 8);
                acc_o[dt] = __builtin_amdgcn_mfma_f32_16x16x32_bf16(pa, vb, acc_o[dt], 0, 0, 0);
            }
        }
    }

    #pragma unroll
    for (int r = 0; r < 4; ++r) {
        const float invl = (lrun[r] > 0.0f) ? (1.0f / lrun[r]) : 0.0f;
        const int qg = q0 + l4 * 4 + r;
        bf16* op = att + (tokbase + qg) * 256 + hh * 32 + l15;
        op[0]  = __float2bfloat16(acc_o[0][r] * invl);
        op[16] = __float2bfloat16(acc_o[1][r] * invl);
    }
}

// ---------------- gather ----------------
__global__ __launch_bounds__(256) void gather_kernel(
    const float* __restrict__ h, const int* __restrict__ ind, float* __restrict__ out)
{
    int b = blockIdx.x;
    int tid = threadIdx.x;
    out[(b * 2 + 0) * 256 + tid] = h[(b * NTOK + 0) * 256 + tid];
    out[(b * 2 + 1) * 256 + tid] = h[(b * NTOK + ind[b] + 1) * 256 + tid];
}

extern "C" void kernel_launch(void* const* d_in, const int* in_sizes, int n_in,
                              void* d_out, int out_size, void* d_ws, size_t ws_size,
                              hipStream_t stream)
{
    const float* x    = (const float*)d_in[0];
    const int*   ind  = (const int*)d_in[2];
    const float* cls1 = (const float*)d_in[3];
    const float* cls2 = (const float*)d_in[4];
    const float* Wqkv = (const float*)d_in[5];
    const float* bqkv = (const float*)d_in[6];
    const float* Wo   = (const float*)d_in[7];
    const float* bo   = (const float*)d_in[8];
    const float* g1   = (const float*)d_in[9];
    const float* be1  = (const float*)d_in[10];
    const float* W1   = (const float*)d_in[11];
    const float* bf1  = (const float*)d_in[12];
    const float* W2   = (const float*)d_in[13];
    const float* bf2  = (const float*)d_in[14];
    const float* g2   = (const float*)d_in[15];
    const float* be2  = (const float*)d_in[16];
    float* out = (float*)d_out;

    // ---- workspace layout ----
    float* ws   = (float*)d_ws;
    float* h    = ws;                       // 1,048,576 f32
    float* tmp  = h + 1048576;              // 1,048,576 f32
    bf16* hb    = (bf16*)(tmp + 1048576);   // 1,048,576 bf16
    bf16* qkvb  = hb + 1048576;             // 3,145,728
    bf16* vTb   = qkvb + 3145728;           // 1,048,576
    bf16* attb  = vTb + 1048576;            // 1,048,576
    bf16* ffb   = attb + 1048576;           // 8,388,608
    bf16* wqkvb = ffb + 8388608;            // 1,179,648
    bf16* wob   = wqkvb + 1179648;          // 393,216
    bf16* w1b   = wob + 393216;             // 3,145,728
    bf16* w2b   = w1b + 3145728;            // 3,145,728

    const int M = BATCH * NTOK;             // 4096

    cast4_kernel<<<7680, 256, 0, stream>>>(Wqkv, wqkvb, Wo, wob, W1, w1b, W2, w2b);
    embed_kernel<<<M, 256, 0, stream>>>(x, cls1, cls2, ind, h, hb);

    for (int l = 0; l < NLAYER; ++l) {
        const bf16*  Wqkv_l = wqkvb + (size_t)l * 196608;
        const float* bqkv_l = bqkv + (size_t)l * 768;
        const bf16*  Wo_l   = wob + (size_t)l * 65536;
        const float* bo_l   = bo + (size_t)l * 256;
        const float* g1_l   = g1 + (size_t)l * 256;
        const float* be1_l  = be1 + (size_t)l * 256;
        const bf16*  W1_l   = w1b + (size_t)l * 524288;
        const float* b1_l   = bf1 + (size_t)l * 2048;
        const bf16*  W2_l   = w2b + (size_t)l * 524288;
        const float* b2_l   = bf2 + (size_t)l * 256;
        const float* g2_l   = g2 + (size_t)l * 256;
        const float* be2_l  = be2 + (size_t)l * 256;

        // qkvb = hb @ Wqkv^T + bqkv ; V-part redirected to vT layout
        mfma_gemm<2, 4, 0, 0, 0, 1, 1><<<(M / 64) * (768 / 128), 256, 0, stream>>>(
            hb, Wqkv_l, bqkv_l, nullptr, nullptr, qkvb, vTb, M, 768, 256);
        // attb = softmax(qk^T + seg-bias) v   (barrier-free)
        attn_mfma_kernel<<<BATCH * 8 * 16, 256, 0, stream>>>(qkvb, vTb, attb, ind);
        // h, hb = LN1(attb @ Wo^T + bo + h)   (fused 8-wave split-K; K=256 is cheap)
        gemm256_ln8_kernel<256><<<M / 16, 512, 0, stream>>>(
            attb, Wo_l, bo_l, g1_l, be1_l, h, hb);
        // ffb = relu(hb @ W1^T + b1)
        mfma_gemm<2, 4, 1, 0, 0, 1, 0><<<(M / 64) * (2048 / 128), 256, 0, stream>>>(
            hb, W1_l, b1_l, nullptr, nullptr, ffb, nullptr, M, 2048, 256);
        // tmp = ffb @ W2^T + b2 + h           (staged, double-buffered 64x64 tile)
        mfma_gemm<2, 2, 0, 1, 1, 0, 0><<<(M / 64) * (256 / 64), 256, 0, stream>>>(
            ffb, W2_l, b2_l, h, tmp, nullptr, nullptr, M, 256, 2048);
        // h, hb = LN2(tmp)
        ln_kernel<<<M / 4, 256, 0, stream>>>(tmp, g2_l, be2_l, h, hb);
    }

    gather_kernel<<<BATCH, 256, 0, stream>>>(h, ind, out);
}

// Round 10
// 541.708 us; speedup vs baseline: 1.3088x; 1.0096x over previous
//
#include <hip/hip_runtime.h>
#include <hip/hip_bf16.h>
#include <math.h>

typedef __hip_bfloat16 bf16;
typedef short bf16x8 __attribute__((ext_vector_type(8)));
typedef short short4v __attribute__((ext_vector_type(4)));
typedef float f32x4 __attribute__((ext_vector_type(4)));

#define D_MODEL 256
#define NTOK 1024
#define SEQ 1022
#define BATCH 4
#define NLAYER 6

// ---- async global->LDS 16B helper ----
__device__ inline void gload_lds16(const void* g, void* l) {
    __builtin_amdgcn_global_load_lds(
        (const __attribute__((address_space(1))) void*)g,
        (__attribute__((address_space(3))) void*)l, 16, 0, 0);
}

// ---------------- merged weight fp32 -> bf16 cast ----------------
__global__ __launch_bounds__(256) void cast4_kernel(
    const float* __restrict__ s0, bf16* __restrict__ d0,
    const float* __restrict__ s1, bf16* __restrict__ d1,
    const float* __restrict__ s2, bf16* __restrict__ d2,
    const float* __restrict__ s3, bf16* __restrict__ d3)
{
    const int bid = blockIdx.x;
    const float* s; bf16* d; int base;
    if (bid < 1152)      { s = s0; d = d0; base = bid; }
    else if (bid < 1536) { s = s1; d = d1; base = bid - 1152; }
    else if (bid < 4608) { s = s2; d = d2; base = bid - 1536; }
    else                 { s = s3; d = d3; base = bid - 4608; }
    const int i = (base * 256 + threadIdx.x) * 4;
    f32x4 v = *(const f32x4*)(s + i);
    d[i + 0] = __float2bfloat16(v[0]);
    d[i + 1] = __float2bfloat16(v[1]);
    d[i + 2] = __float2bfloat16(v[2]);
    d[i + 3] = __float2bfloat16(v[3]);
}

// ---------------- embed ----------------
__global__ __launch_bounds__(256) void embed_kernel(
    const float* __restrict__ x, const float* __restrict__ cls1,
    const float* __restrict__ cls2, const int* __restrict__ ind,
    float* __restrict__ h, bf16* __restrict__ hb)
{
    int i = blockIdx.x * 256 + threadIdx.x;
    int d = i & 255;
    int pos = (i >> 8) & 1023;
    int b = i >> 18;
    int idx = ind[b];
    float v;
    if (pos == 0) v = cls1[d];
    else if (pos == idx + 1) v = cls2[d];
    else if (pos <= idx) v = x[(b * SEQ + pos - 1) * D_MODEL + d];
    else v = x[(b * SEQ + pos - 2) * D_MODEL + d];
    int p = d >> 1;
    float freq = expf(-(float)p * (logf(10000.0f) / 128.0f));
    float ang = (float)pos * freq;
    v += (d & 1) ? cosf(ang) : sinf(ang);
    h[i] = v;
    hb[i] = __float2bfloat16(v);
}

// ---------------- bf16 MFMA NT GEMM (qkv / W1 / W2) ----------------
template<int MR, int NR, int RELU, int HAS_RES, int WF32, int WBF16, int WVT>
__global__ __launch_bounds__(256) void mfma_gemm(
    const bf16* __restrict__ A, const bf16* __restrict__ W,
    const float* __restrict__ bias, const float* __restrict__ R,
    float* __restrict__ Cf, bf16* __restrict__ Cb, bf16* __restrict__ vTb,
    int M, int N, int K)
{
    constexpr int BM = MR * 32, BN = NR * 32;
    constexpr int ACH = BM * 4;
    constexpr int BCH = BN * 4;
    __shared__ bf16 As[2][BM * 32];
    __shared__ bf16 Bs[2][BN * 32];
    const int ntile = N / BN;
    const int bx = blockIdx.x % ntile, by = blockIdx.x / ntile;
    const int row0 = by * BM, col0 = bx * BN;
    const int tid = threadIdx.x, lane = tid & 63, wave = tid >> 6;
    const int wr = wave >> 1, wc = wave & 1;
    const int l15 = lane & 15, l4 = lane >> 4;

    f32x4 acc[MR][NR];
    #pragma unroll
    for (int m = 0; m < MR; ++m)
        #pragma unroll
        for (int n = 0; n < NR; ++n) acc[m][n] = (f32x4)0.0f;

    const int nk = K / 32;

    auto stage = [&](int buf, int t) {
        const int k0 = t * 32;
        #pragma unroll
        for (int p = 0; p < ACH / 256; ++p) {
            const int cbase = p * 256 + wave * 64;
            const int chunk = cbase + lane;
            const int r = chunk >> 2, c = chunk & 3;
            gload_lds16(A + (size_t)(row0 + r) * K + k0 + c * 8, &As[buf][cbase * 8]);
        }
        #pragma unroll
        for (int p = 0; p < BCH / 256; ++p) {
            const int cbase = p * 256 + wave * 64;
            const int chunk = cbase + lane;
            const int r = chunk >> 2, c = chunk & 3;
            gload_lds16(W + (size_t)(col0 + r) * K + k0 + c * 8, &Bs[buf][cbase * 8]);
        }
    };

    stage(0, 0);
    __syncthreads();
    int cur = 0;
    for (int t = 0; t < nk; ++t) {
        if (t + 1 < nk) stage(cur ^ 1, t + 1);
        bf16x8 af[MR], bfr[NR];
        #pragma unroll
        for (int m = 0; m < MR; ++m)
            af[m] = *(const bf16x8*)&As[cur][(wr * MR * 16 + m * 16 + l15) * 32 + l4 * 8];
        #pragma unroll
        for (int n = 0; n < NR; ++n)
            bfr[n] = *(const bf16x8*)&Bs[cur][(wc * NR * 16 + n * 16 + l15) * 32 + l4 * 8];
        #pragma unroll
        for (int m = 0; m < MR; ++m)
            #pragma unroll
            for (int n = 0; n < NR; ++n)
                acc[m][n] = __builtin_amdgcn_mfma_f32_16x16x32_bf16(af[m], bfr[n], acc[m][n], 0, 0, 0);
        __syncthreads();
        cur ^= 1;
    }

    #pragma unroll
    for (int m = 0; m < MR; ++m) {
        #pragma unroll
        for (int n = 0; n < NR; ++n) {
            const int col = col0 + wc * NR * 16 + n * 16 + l15;
            const float bv = bias[col];
            #pragma unroll
            for (int r = 0; r < 4; ++r) {
                const int row = row0 + wr * MR * 16 + m * 16 + l4 * 4 + r;
                float v = acc[m][n][r] + bv;
                if (HAS_RES) v += R[(size_t)row * N + col];
                if (RELU) v = fmaxf(v, 0.0f);
                if (WF32) Cf[(size_t)row * N + col] = v;
                if (WBF16) {
                    if (WVT && col >= 512) {
                        const int hh = (col >> 5) - 16, d = col & 31;
                        const int bb = row >> 10, tt = row & 1023;
                        vTb[(((size_t)bb * 8 + hh) * 32 + d) * 1024 + tt] = __float2bfloat16(v);
                    } else {
                        Cb[(size_t)row * N + col] = __float2bfloat16(v);
                    }
                }
            }
        }
    }
}

// ---------------- fused N=256 GEMM + bias + residual + LayerNorm (Wo path) ----------------
template<int K>
__global__ __launch_bounds__(512) void gemm256_ln8_kernel(
    const bf16* __restrict__ A, const bf16* __restrict__ W,
    const float* __restrict__ bias, const float* __restrict__ g,
    const float* __restrict__ be, float* __restrict__ h, bf16* __restrict__ hb)
{
    constexpr int KW = K / 8;
    constexpr int NSTEP = KW / 32;
    __shared__ float part[4][16][260];
    const int tid = threadIdx.x, lane = tid & 63, wave = tid >> 6;
    const int l15 = lane & 15, l4 = lane >> 4;
    const int row0 = blockIdx.x * 16;

    f32x4 acc[16];
    #pragma unroll
    for (int n = 0; n < 16; ++n) acc[n] = (f32x4)0.0f;
    #pragma unroll
    for (int s = 0; s < NSTEP; ++s) {
        const int kk = wave * KW + s * 32;
        const bf16x8 af = *(const bf16x8*)(A + (size_t)(row0 + l15) * K + kk + l4 * 8);
        #pragma unroll
        for (int n = 0; n < 16; ++n) {
            const bf16x8 bfr = *(const bf16x8*)(W + (size_t)(n * 16 + l15) * K + kk + l4 * 8);
            acc[n] = __builtin_amdgcn_mfma_f32_16x16x32_bf16(af, bfr, acc[n], 0, 0, 0);
        }
    }
    if (wave < 4) {
        #pragma unroll
        for (int n = 0; n < 16; ++n)
            #pragma unroll
            for (int r = 0; r < 4; ++r)
                part[wave][l4 * 4 + r][n * 16 + l15] = acc[n][r];
    }
    __syncthreads();
    if (wave >= 4) {
        #pragma unroll
        for (int n = 0; n < 16; ++n)
            #pragma unroll
            for (int r = 0; r < 4; ++r)
                part[wave - 4][l4 * 4 + r][n * 16 + l15] += acc[n][r];
    }
    __syncthreads();

    const int row = tid >> 5, c8 = (tid & 31) * 8;
    f32x4 v0 = *(const f32x4*)&part[0][row][c8];
    f32x4 v1 = *(const f32x4*)&part[0][row][c8 + 4];
    #pragma unroll
    for (int w = 1; w < 4; ++w) {
        v0 += *(const f32x4*)&part[w][row][c8];
        v1 += *(const f32x4*)&part[w][row][c8 + 4];
    }
    float* hrow = h + (size_t)(row0 + row) * 256 + c8;
    v0 += *(const f32x4*)(bias + c8)     + *(const f32x4*)(hrow);
    v1 += *(const f32x4*)(bias + c8 + 4) + *(const f32x4*)(hrow + 4);
    float s1 = (v0[0] + v0[1]) + (v0[2] + v0[3]) + (v1[0] + v1[1]) + (v1[2] + v1[3]);
    #pragma unroll
    for (int off = 16; off >= 1; off >>= 1) s1 += __shfl_xor(s1, off);
    const float mu = s1 * (1.0f / 256.0f);
    float s2 = 0.0f;
    #pragma unroll
    for (int q = 0; q < 4; ++q) { float d0 = v0[q] - mu, d1 = v1[q] - mu; s2 += d0 * d0 + d1 * d1; }
    #pragma unroll
    for (int off = 16; off >= 1; off >>= 1) s2 += __shfl_xor(s2, off);
    const float inv = 1.0f / sqrtf(s2 * (1.0f / 256.0f) + 1e-5f);
    short* hbrow = (short*)hb + (size_t)(row0 + row) * 256 + c8;
    const f32x4 gv0 = *(const f32x4*)(g + c8),  gv1 = *(const f32x4*)(g + c8 + 4);
    const f32x4 ev0 = *(const f32x4*)(be + c8), ev1 = *(const f32x4*)(be + c8 + 4);
    f32x4 y0, y1; short4v p0, p1;
    #pragma unroll
    for (int q = 0; q < 4; ++q) {
        y0[q] = (v0[q] - mu) * inv * gv0[q] + ev0[q];
        y1[q] = (v1[q] - mu) * inv * gv1[q] + ev1[q];
        p0[q] = __builtin_bit_cast(short, __float2bfloat16(y0[q]));
        p1[q] = __builtin_bit_cast(short, __float2bfloat16(y1[q]));
    }
    *(f32x4*)(hrow) = y0;  *(f32x4*)(hrow + 4) = y1;
    *(short4v*)(hbrow) = p0;  *(short4v*)(hbrow + 4) = p1;
}

// ---------------- LayerNorm: one wave per row ----------------
__global__ __launch_bounds__(256) void ln_kernel(
    const float* __restrict__ X, const float* __restrict__ g,
    const float* __restrict__ bb, float* __restrict__ Y, bf16* __restrict__ Yb)
{
    const int row = blockIdx.x * 4 + (threadIdx.x >> 6);
    const int lane = threadIdx.x & 63;
    const f32x4 xv = *(const f32x4*)(X + (size_t)row * 256 + lane * 4);
    float s = (xv[0] + xv[1]) + (xv[2] + xv[3]);
    #pragma unroll
    for (int off = 32; off >= 1; off >>= 1) s += __shfl_xor(s, off);
    const float mu = s * (1.0f / 256.0f);
    f32x4 dv;
    float s2 = 0.0f;
    #pragma unroll
    for (int e = 0; e < 4; ++e) { dv[e] = xv[e] - mu; s2 += dv[e] * dv[e]; }
    #pragma unroll
    for (int off = 32; off >= 1; off >>= 1) s2 += __shfl_xor(s2, off);
    const float inv = 1.0f / sqrtf(s2 * (1.0f / 256.0f) + 1e-5f);
    const f32x4 gv = *(const f32x4*)(g + lane * 4);
    const f32x4 bv = *(const f32x4*)(bb + lane * 4);
    f32x4 y;
    short4v pk;
    #pragma unroll
    for (int e = 0; e < 4; ++e) {
        y[e] = dv[e] * inv * gv[e] + bv[e];
        pk[e] = __builtin_bit_cast(short, __float2bfloat16(y[e]));
    }
    *(f32x4*)(Y + (size_t)row * 256 + lane * 4) = y;
    *(short4v*)((short*)Yb + (size_t)row * 256 + lane * 4) = pk;
}

// ---------------- split-K barrier-lite MFMA flash attention ----------------
// grid: B*H*32 blocks, 256 thr = 4 waves. Block = 32 q-rows = 2 strips of 16.
// Wave w: strip s=w>>1, k-half kh=w&1. Each wave runs the barrier-free flash
// loop over HALF the k-tiles; partials (o, m, l) merged through LDS at the end.
__global__ __launch_bounds__(256) void attn_mfma_kernel(
    const bf16* __restrict__ qkvb, const bf16* __restrict__ vT,
    bf16* __restrict__ att, const int* __restrict__ ind)
{
    __shared__ bf16 Ps[4][16][72];
    __shared__ float Opart[4][64][8];
    __shared__ float MLpart[4][64][8];
    const int qt = blockIdx.x & 31;
    const int hh = (blockIdx.x >> 5) & 7;
    const int b  = blockIdx.x >> 8;
    const int idx = ind[b];
    const int segEnd = NTOK - ind[4 + b];
    const int tid = threadIdx.x, lane = tid & 63, wave = tid >> 6;
    const int strip = wave >> 1, kh = wave & 1;
    const int l15 = lane & 15, l4 = lane >> 4;
    const int q0 = qt * 32 + strip * 16;
    const size_t tokbase = (size_t)b * NTOK;
    const bf16* vTh = vT + (((size_t)b * 8 + hh) * 32) * 1024;
    const float scale = 0.17677669529663687f;

    const bf16x8 qfrag = *(const bf16x8*)(qkvb + (tokbase + q0 + l15) * 768 + hh * 32 + l4 * 8);

    f32x4 acc_o[2];
    acc_o[0] = (f32x4)0.0f; acc_o[1] = (f32x4)0.0f;
    float mrun[4], lrun[4];
    bool v1q[4], v2q[4];
    #pragma unroll
    for (int r = 0; r < 4; ++r) {
        mrun[r] = -1e30f; lrun[r] = 0.0f;
        const int qg = q0 + l4 * 4 + r;
        v1q[r] = (qg <= idx);
        v2q[r] = (qg > idx) && (qg < segEnd);
    }

    const int kbeg = (q0 <= idx) ? 0 : (idx + 1);
    const int kend = (q0 + 15 > idx) ? segEnd : (idx + 1);
    const int t0 = kbeg & ~63;
    const int T = (kend - t0 + 63) >> 6;       // total 64-k tiles for this strip
    const int i0 = kh ? (T >> 1) : 0;
    const int i1 = kh ? T : (T >> 1);

    for (int i = i0; i < i1; ++i) {
        const int k0 = t0 + (i << 6);
        f32x4 sc[4];
        #pragma unroll
        for (int kt = 0; kt < 4; ++kt) {
            const bf16x8 kf = *(const bf16x8*)
                (qkvb + (tokbase + k0 + kt * 16 + l15) * 768 + 256 + hh * 32 + l4 * 8);
            sc[kt] = __builtin_amdgcn_mfma_f32_16x16x32_bf16(qfrag, kf, (f32x4)0.0f, 0, 0, 0);
        }
        float mloc[4] = {-1e30f, -1e30f, -1e30f, -1e30f};
        #pragma unroll
        for (int kt = 0; kt < 4; ++kt) {
            const int k = k0 + kt * 16 + l15;
            const bool v1k = (k <= idx);
            const bool v2k = (k > idx) && (k < segEnd);
            #pragma unroll
            for (int r = 0; r < 4; ++r) {
                const bool ok = (v1q[r] && v1k) || (v2q[r] && v2k);
                const float s = ok ? sc[kt][r] * scale : -1e30f;
                sc[kt][r] = s;
                mloc[r] = fmaxf(mloc[r], s);
            }
        }
        #pragma unroll
        for (int r = 0; r < 4; ++r) {
            mloc[r] = fmaxf(mloc[r], __shfl_xor(mloc[r], 1));
            mloc[r] = fmaxf(mloc[r], __shfl_xor(mloc[r], 2));
            mloc[r] = fmaxf(mloc[r], __shfl_xor(mloc[r], 4));
            mloc[r] = fmaxf(mloc[r], __shfl_xor(mloc[r], 8));
            const float mnew = fmaxf(mrun[r], mloc[r]);
            const float c = __expf(mrun[r] - mnew);
            mrun[r] = mnew;
            mloc[r] = c;            // corr
        }
        float psum[4] = {0.0f, 0.0f, 0.0f, 0.0f};
        #pragma unroll
        for (int kt = 0; kt < 4; ++kt) {
            #pragma unroll
            for (int r = 0; r < 4; ++r) {
                const float s = sc[kt][r];
                const float p = (s > -5e29f) ? __expf(s - mrun[r]) : 0.0f;
                psum[r] += p;
                Ps[wave][l4 * 4 + r][kt * 16 + l15] = __float2bfloat16(p);
            }
        }
        #pragma unroll
        for (int r = 0; r < 4; ++r) {
            float ps = psum[r];
            ps += __shfl_xor(ps, 1); ps += __shfl_xor(ps, 2);
            ps += __shfl_xor(ps, 4); ps += __shfl_xor(ps, 8);
            lrun[r] = lrun[r] * mloc[r] + ps;
            acc_o[0][r] *= mloc[r];
            acc_o[1][r] *= mloc[r];
        }
        #pragma unroll
        for (int ks = 0; ks < 2; ++ks) {
            const bf16x8 pa = *(const bf16x8*)&Ps[wave][l15][ks * 32 + l4 * 8];
            #pragma unroll
            for (int dt = 0; dt < 2; ++dt) {
                const bf16x8 vb = *(const bf16x8*)
                    (vTh + (size_t)(dt * 16 + l15) * 1024 + k0 + ks * 32 + l4 * 8);
                acc_o[dt] = __builtin_amdgcn_mfma_f32_16x16x32_bf16(pa, vb, acc_o[dt], 0, 0, 0);
            }
        }
    }

    // write partials and merge the two k-halves of each strip
    #pragma unroll
    for (int r = 0; r < 4; ++r) {
        Opart[wave][lane][r]     = acc_o[0][r];
        Opart[wave][lane][4 + r] = acc_o[1][r];
        MLpart[wave][lane][r]     = mrun[r];
        MLpart[wave][lane][4 + r] = lrun[r];
    }
    __syncthreads();
    if (kh == 0) {
        #pragma unroll
        for (int r = 0; r < 4; ++r) {
            const float m1 = MLpart[wave + 1][lane][r];
            const float l1 = MLpart[wave + 1][lane][4 + r];
            const float ms = fmaxf(mrun[r], m1);
            const float c0 = __expf(mrun[r] - ms);
            const float c1 = __expf(m1 - ms);
            const float lt = lrun[r] * c0 + l1 * c1;
            const float invl = (lt > 0.0f) ? (1.0f / lt) : 0.0f;
            const float o0 = (acc_o[0][r] * c0 + Opart[wave + 1][lane][r] * c1) * invl;
            const float o1 = (acc_o[1][r] * c0 + Opart[wave + 1][lane][4 + r] * c1) * invl;
            const int qg = q0 + l4 * 4 + r;
            bf16* op = att + (tokbase + qg) * 256 + hh * 32 + l15;
            op[0]  = __float2bfloat16(o0);
            op[16] = __float2bfloat16(o1);
        }
    }
}

// ---------------- gather ----------------
__global__ __launch_bounds__(256) void gather_kernel(
    const float* __restrict__ h, const int* __restrict__ ind, float* __restrict__ out)
{
    int b = blockIdx.x;
    int tid = threadIdx.x;
    out[(b * 2 + 0) * 256 + tid] = h[(b * NTOK + 0) * 256 + tid];
    out[(b * 2 + 1) * 256 + tid] = h[(b * NTOK + ind[b] + 1) * 256 + tid];
}

extern "C" void kernel_launch(void* const* d_in, const int* in_sizes, int n_in,
                              void* d_out, int out_size, void* d_ws, size_t ws_size,
                              hipStream_t stream)
{
    const float* x    = (const float*)d_in[0];
    const int*   ind  = (const int*)d_in[2];
    const float* cls1 = (const float*)d_in[3];
    const float* cls2 = (const float*)d_in[4];
    const float* Wqkv = (const float*)d_in[5];
    const float* bqkv = (const float*)d_in[6];
    const float* Wo   = (const float*)d_in[7];
    const float* bo   = (const float*)d_in[8];
    const float* g1   = (const float*)d_in[9];
    const float* be1  = (const float*)d_in[10];
    const float* W1   = (const float*)d_in[11];
    const float* bf1  = (const float*)d_in[12];
    const float* W2   = (const float*)d_in[13];
    const float* bf2  = (const float*)d_in[14];
    const float* g2   = (const float*)d_in[15];
    const float* be2  = (const float*)d_in[16];
    float* out = (float*)d_out;

    // ---- workspace layout ----
    float* ws   = (float*)d_ws;
    float* h    = ws;                       // 1,048,576 f32
    float* tmp  = h + 1048576;              // 1,048,576 f32
    bf16* hb    = (bf16*)(tmp + 1048576);   // 1,048,576 bf16
    bf16* qkvb  = hb + 1048576;             // 3,145,728
    bf16* vTb   = qkvb + 3145728;           // 1,048,576
    bf16* attb  = vTb + 1048576;            // 1,048,576
    bf16* ffb   = attb + 1048576;           // 8,388,608
    bf16* wqkvb = ffb + 8388608;            // 1,179,648
    bf16* wob   = wqkvb + 1179648;          // 393,216
    bf16* w1b   = wob + 393216;             // 3,145,728
    bf16* w2b   = w1b + 3145728;            // 3,145,728

    const int M = BATCH * NTOK;             // 4096

    cast4_kernel<<<7680, 256, 0, stream>>>(Wqkv, wqkvb, Wo, wob, W1, w1b, W2, w2b);
    embed_kernel<<<M, 256, 0, stream>>>(x, cls1, cls2, ind, h, hb);

    for (int l = 0; l < NLAYER; ++l) {
        const bf16*  Wqkv_l = wqkvb + (size_t)l * 196608;
        const float* bqkv_l = bqkv + (size_t)l * 768;
        const bf16*  Wo_l   = wob + (size_t)l * 65536;
        const float* bo_l   = bo + (size_t)l * 256;
        const float* g1_l   = g1 + (size_t)l * 256;
        const float* be1_l  = be1 + (size_t)l * 256;
        const bf16*  W1_l   = w1b + (size_t)l * 524288;
        const float* b1_l   = bf1 + (size_t)l * 2048;
        const bf16*  W2_l   = w2b + (size_t)l * 524288;
        const float* b2_l   = bf2 + (size_t)l * 256;
        const float* g2_l   = g2 + (size_t)l * 256;
        const float* be2_l  = be2 + (size_t)l * 256;

        // qkvb = hb @ Wqkv^T + bqkv ; V-part redirected to vT layout
        mfma_gemm<2, 4, 0, 0, 0, 1, 1><<<(M / 64) * (768 / 128), 256, 0, stream>>>(
            hb, Wqkv_l, bqkv_l, nullptr, nullptr, qkvb, vTb, M, 768, 256);
        // attb = softmax(qk^T + seg-bias) v   (split-K flash, 4 waves/SIMD)
        attn_mfma_kernel<<<BATCH * 8 * 32, 256, 0, stream>>>(qkvb, vTb, attb, ind);
        // h, hb = LN1(attb @ Wo^T + bo + h)
        gemm256_ln8_kernel<256><<<M / 16, 512, 0, stream>>>(
            attb, Wo_l, bo_l, g1_l, be1_l, h, hb);
        // ffb = relu(hb @ W1^T + b1)          (128x128 tiles, grid 512)
        mfma_gemm<4, 4, 1, 0, 0, 1, 0><<<(M / 128) * (2048 / 128), 256, 0, stream>>>(
            hb, W1_l, b1_l, nullptr, nullptr, ffb, nullptr, M, 2048, 256);
        // tmp = ffb @ W2^T + b2 + h           (staged 64x64, K=2048)
        mfma_gemm<2, 2, 0, 1, 1, 0, 0><<<(M / 64) * (256 / 64), 256, 0, stream>>>(
            ffb, W2_l, b2_l, h, tmp, nullptr, nullptr, M, 256, 2048);
        // h, hb = LN2(tmp)
        ln_kernel<<<M / 4, 256, 0, stream>>>(tmp, g2_l, be2_l, h, hb);
    }

    gather_kernel<<<BATCH, 256, 0, stream>>>(h, ind, out);
}

// Round 11
// 485.623 us; speedup vs baseline: 1.4599x; 1.1155x over previous
//
#include <hip/hip_runtime.h>
#include <hip/hip_bf16.h>
#include <math.h>

typedef __hip_bfloat16 bf16;
typedef short bf16x8 __attribute__((ext_vector_type(8)));
typedef short short4v __attribute__((ext_vector_type(4)));
typedef float f32x4 __attribute__((ext_vector_type(4)));

#define D_MODEL 256
#define NTOK 1024
#define SEQ 1022
#define BATCH 4
#define NLAYER 6

// ---- async global->LDS 16B helper ----
__device__ inline void gload_lds16(const void* g, void* l) {
    __builtin_amdgcn_global_load_lds(
        (const __attribute__((address_space(1))) void*)g,
        (__attribute__((address_space(3))) void*)l, 16, 0, 0);
}

// ---------------- merged weight fp32 -> bf16 cast ----------------
__global__ __launch_bounds__(256) void cast4_kernel(
    const float* __restrict__ s0, bf16* __restrict__ d0,
    const float* __restrict__ s1, bf16* __restrict__ d1,
    const float* __restrict__ s2, bf16* __restrict__ d2,
    const float* __restrict__ s3, bf16* __restrict__ d3)
{
    const int bid = blockIdx.x;
    const float* s; bf16* d; int base;
    if (bid < 1152)      { s = s0; d = d0; base = bid; }
    else if (bid < 1536) { s = s1; d = d1; base = bid - 1152; }
    else if (bid < 4608) { s = s2; d = d2; base = bid - 1536; }
    else                 { s = s3; d = d3; base = bid - 4608; }
    const int i = (base * 256 + threadIdx.x) * 4;
    f32x4 v = *(const f32x4*)(s + i);
    d[i + 0] = __float2bfloat16(v[0]);
    d[i + 1] = __float2bfloat16(v[1]);
    d[i + 2] = __float2bfloat16(v[2]);
    d[i + 3] = __float2bfloat16(v[3]);
}

// ---------------- embed ----------------
__global__ __launch_bounds__(256) void embed_kernel(
    const float* __restrict__ x, const float* __restrict__ cls1,
    const float* __restrict__ cls2, const int* __restrict__ ind,
    float* __restrict__ h, bf16* __restrict__ hb)
{
    int i = blockIdx.x * 256 + threadIdx.x;
    int d = i & 255;
    int pos = (i >> 8) & 1023;
    int b = i >> 18;
    int idx = ind[b];
    float v;
    if (pos == 0) v = cls1[d];
    else if (pos == idx + 1) v = cls2[d];
    else if (pos <= idx) v = x[(b * SEQ + pos - 1) * D_MODEL + d];
    else v = x[(b * SEQ + pos - 2) * D_MODEL + d];
    int p = d >> 1;
    float freq = expf(-(float)p * (logf(10000.0f) / 128.0f));
    float ang = (float)pos * freq;
    v += (d & 1) ? cosf(ang) : sinf(ang);
    h[i] = v;
    hb[i] = __float2bfloat16(v);
}

// ---------------- bf16 MFMA NT GEMM (qkv / W1 / W2-splitK) ----------------
// SPLITK>1: blockIdx.x = kslice*tiles + tile; each slice sums K/SPLITK and
// writes a raw fp32 partial at Cf + kslice*M*N (no bias/res/relu).
template<int MR, int NR, int RELU, int HAS_RES, int WF32, int WBF16, int WVT, int SPLITK>
__global__ __launch_bounds__(256) void mfma_gemm(
    const bf16* __restrict__ A, const bf16* __restrict__ W,
    const float* __restrict__ bias, const float* __restrict__ R,
    float* __restrict__ Cf, bf16* __restrict__ Cb, bf16* __restrict__ vTb,
    int M, int N, int K)
{
    constexpr int BM = MR * 32, BN = NR * 32;
    constexpr int ACH = BM * 4;
    constexpr int BCH = BN * 4;
    __shared__ bf16 As[2][BM * 32];
    __shared__ bf16 Bs[2][BN * 32];
    const int ntile = N / BN;
    const int tiles = (M / BM) * ntile;
    const int ks = (SPLITK > 1) ? (blockIdx.x / tiles) : 0;
    const int bidt = (SPLITK > 1) ? (blockIdx.x % tiles) : blockIdx.x;
    const int bx = bidt % ntile, by = bidt / ntile;
    const int row0 = by * BM, col0 = bx * BN;
    const int KS = K / SPLITK;
    const int kbase = ks * KS;
    const int tid = threadIdx.x, lane = tid & 63, wave = tid >> 6;
    const int wr = wave >> 1, wc = wave & 1;
    const int l15 = lane & 15, l4 = lane >> 4;

    f32x4 acc[MR][NR];
    #pragma unroll
    for (int m = 0; m < MR; ++m)
        #pragma unroll
        for (int n = 0; n < NR; ++n) acc[m][n] = (f32x4)0.0f;

    const int nk = KS / 32;

    auto stage = [&](int buf, int t) {
        const int k0 = kbase + t * 32;
        #pragma unroll
        for (int p = 0; p < ACH / 256; ++p) {
            const int cbase = p * 256 + wave * 64;
            const int chunk = cbase + lane;
            const int r = chunk >> 2, c = chunk & 3;
            gload_lds16(A + (size_t)(row0 + r) * K + k0 + c * 8, &As[buf][cbase * 8]);
        }
        #pragma unroll
        for (int p = 0; p < BCH / 256; ++p) {
            const int cbase = p * 256 + wave * 64;
            const int chunk = cbase + lane;
            const int r = chunk >> 2, c = chunk & 3;
            gload_lds16(W + (size_t)(col0 + r) * K + k0 + c * 8, &Bs[buf][cbase * 8]);
        }
    };

    stage(0, 0);
    __syncthreads();
    int cur = 0;
    for (int t = 0; t < nk; ++t) {
        if (t + 1 < nk) stage(cur ^ 1, t + 1);
        bf16x8 af[MR], bfr[NR];
        #pragma unroll
        for (int m = 0; m < MR; ++m)
            af[m] = *(const bf16x8*)&As[cur][(wr * MR * 16 + m * 16 + l15) * 32 + l4 * 8];
        #pragma unroll
        for (int n = 0; n < NR; ++n)
            bfr[n] = *(const bf16x8*)&Bs[cur][(wc * NR * 16 + n * 16 + l15) * 32 + l4 * 8];
        #pragma unroll
        for (int m = 0; m < MR; ++m)
            #pragma unroll
            for (int n = 0; n < NR; ++n)
                acc[m][n] = __builtin_amdgcn_mfma_f32_16x16x32_bf16(af[m], bfr[n], acc[m][n], 0, 0, 0);
        __syncthreads();
        cur ^= 1;
    }

    #pragma unroll
    for (int m = 0; m < MR; ++m) {
        #pragma unroll
        for (int n = 0; n < NR; ++n) {
            const int col = col0 + wc * NR * 16 + n * 16 + l15;
            const float bv = (SPLITK > 1) ? 0.0f : bias[col];
            #pragma unroll
            for (int r = 0; r < 4; ++r) {
                const int row = row0 + wr * MR * 16 + m * 16 + l4 * 4 + r;
                float v = acc[m][n][r] + bv;
                if (HAS_RES) v += R[(size_t)row * N + col];
                if (RELU) v = fmaxf(v, 0.0f);
                if (WF32) Cf[(size_t)ks * M * N + (size_t)row * N + col] = v;
                if (WBF16) {
                    if (WVT && col >= 512) {
                        const int hh = (col >> 5) - 16, d = col & 31;
                        const int bb = row >> 10, tt = row & 1023;
                        vTb[(((size_t)bb * 8 + hh) * 32 + d) * 1024 + tt] = __float2bfloat16(v);
                    } else {
                        Cb[(size_t)row * N + col] = __float2bfloat16(v);
                    }
                }
            }
        }
    }
}

// ---------------- fused N=256 GEMM + bias + residual + LayerNorm (Wo path) ----------------
template<int K>
__global__ __launch_bounds__(512) void gemm256_ln8_kernel(
    const bf16* __restrict__ A, const bf16* __restrict__ W,
    const float* __restrict__ bias, const float* __restrict__ g,
    const float* __restrict__ be, float* __restrict__ h, bf16* __restrict__ hb)
{
    constexpr int KW = K / 8;
    constexpr int NSTEP = KW / 32;
    __shared__ float part[4][16][260];
    const int tid = threadIdx.x, lane = tid & 63, wave = tid >> 6;
    const int l15 = lane & 15, l4 = lane >> 4;
    const int row0 = blockIdx.x * 16;

    f32x4 acc[16];
    #pragma unroll
    for (int n = 0; n < 16; ++n) acc[n] = (f32x4)0.0f;
    #pragma unroll
    for (int s = 0; s < NSTEP; ++s) {
        const int kk = wave * KW + s * 32;
        const bf16x8 af = *(const bf16x8*)(A + (size_t)(row0 + l15) * K + kk + l4 * 8);
        #pragma unroll
        for (int n = 0; n < 16; ++n) {
            const bf16x8 bfr = *(const bf16x8*)(W + (size_t)(n * 16 + l15) * K + kk + l4 * 8);
            acc[n] = __builtin_amdgcn_mfma_f32_16x16x32_bf16(af, bfr, acc[n], 0, 0, 0);
        }
    }
    if (wave < 4) {
        #pragma unroll
        for (int n = 0; n < 16; ++n)
            #pragma unroll
            for (int r = 0; r < 4; ++r)
                part[wave][l4 * 4 + r][n * 16 + l15] = acc[n][r];
    }
    __syncthreads();
    if (wave >= 4) {
        #pragma unroll
        for (int n = 0; n < 16; ++n)
            #pragma unroll
            for (int r = 0; r < 4; ++r)
                part[wave - 4][l4 * 4 + r][n * 16 + l15] += acc[n][r];
    }
    __syncthreads();

    const int row = tid >> 5, c8 = (tid & 31) * 8;
    f32x4 v0 = *(const f32x4*)&part[0][row][c8];
    f32x4 v1 = *(const f32x4*)&part[0][row][c8 + 4];
    #pragma unroll
    for (int w = 1; w < 4; ++w) {
        v0 += *(const f32x4*)&part[w][row][c8];
        v1 += *(const f32x4*)&part[w][row][c8 + 4];
    }
    float* hrow = h + (size_t)(row0 + row) * 256 + c8;
    v0 += *(const f32x4*)(bias + c8)     + *(const f32x4*)(hrow);
    v1 += *(const f32x4*)(bias + c8 + 4) + *(const f32x4*)(hrow + 4);
    float s1 = (v0[0] + v0[1]) + (v0[2] + v0[3]) + (v1[0] + v1[1]) + (v1[2] + v1[3]);
    #pragma unroll
    for (int off = 16; off >= 1; off >>= 1) s1 += __shfl_xor(s1, off);
    const float mu = s1 * (1.0f / 256.0f);
    float s2 = 0.0f;
    #pragma unroll
    for (int q = 0; q < 4; ++q) { float d0 = v0[q] - mu, d1 = v1[q] - mu; s2 += d0 * d0 + d1 * d1; }
    #pragma unroll
    for (int off = 16; off >= 1; off >>= 1) s2 += __shfl_xor(s2, off);
    const float inv = 1.0f / sqrtf(s2 * (1.0f / 256.0f) + 1e-5f);
    short* hbrow = (short*)hb + (size_t)(row0 + row) * 256 + c8;
    const f32x4 gv0 = *(const f32x4*)(g + c8),  gv1 = *(const f32x4*)(g + c8 + 4);
    const f32x4 ev0 = *(const f32x4*)(be + c8), ev1 = *(const f32x4*)(be + c8 + 4);
    f32x4 y0, y1; short4v p0, p1;
    #pragma unroll
    for (int q = 0; q < 4; ++q) {
        y0[q] = (v0[q] - mu) * inv * gv0[q] + ev0[q];
        y1[q] = (v1[q] - mu) * inv * gv1[q] + ev1[q];
        p0[q] = __builtin_bit_cast(short, __float2bfloat16(y0[q]));
        p1[q] = __builtin_bit_cast(short, __float2bfloat16(y1[q]));
    }
    *(f32x4*)(hrow) = y0;  *(f32x4*)(hrow + 4) = y1;
    *(short4v*)(hbrow) = p0;  *(short4v*)(hbrow + 4) = p1;
}

// ---------------- LayerNorm merge: LN(p0 + p1 + bias + h) -> h, hb ----------------
__global__ __launch_bounds__(256) void ln_merge_kernel(
    const float* __restrict__ P0, const float* __restrict__ P1,
    const float* __restrict__ bias, const float* __restrict__ g,
    const float* __restrict__ bb, float* __restrict__ h, bf16* __restrict__ hb)
{
    const int row = blockIdx.x * 4 + (threadIdx.x >> 6);
    const int lane = threadIdx.x & 63;
    const size_t off = (size_t)row * 256 + lane * 4;
    f32x4 xv = *(const f32x4*)(P0 + off);
    xv += *(const f32x4*)(P1 + off);
    xv += *(const f32x4*)(bias + lane * 4);
    xv += *(const f32x4*)(h + off);
    float s = (xv[0] + xv[1]) + (xv[2] + xv[3]);
    #pragma unroll
    for (int o = 32; o >= 1; o >>= 1) s += __shfl_xor(s, o);
    const float mu = s * (1.0f / 256.0f);
    f32x4 dv;
    float s2 = 0.0f;
    #pragma unroll
    for (int e = 0; e < 4; ++e) { dv[e] = xv[e] - mu; s2 += dv[e] * dv[e]; }
    #pragma unroll
    for (int o = 32; o >= 1; o >>= 1) s2 += __shfl_xor(s2, o);
    const float inv = 1.0f / sqrtf(s2 * (1.0f / 256.0f) + 1e-5f);
    const f32x4 gv = *(const f32x4*)(g + lane * 4);
    const f32x4 bv = *(const f32x4*)(bb + lane * 4);
    f32x4 y;
    short4v pk;
    #pragma unroll
    for (int e = 0; e < 4; ++e) {
        y[e] = dv[e] * inv * gv[e] + bv[e];
        pk[e] = __builtin_bit_cast(short, __float2bfloat16(y[e]));
    }
    *(f32x4*)(h + off) = y;
    *(short4v*)((short*)hb + off) = pk;
}

// ---------------- split-K barrier-lite MFMA flash attention ----------------
__global__ __launch_bounds__(256) void attn_mfma_kernel(
    const bf16* __restrict__ qkvb, const bf16* __restrict__ vT,
    bf16* __restrict__ att, const int* __restrict__ ind)
{
    __shared__ bf16 Ps[4][16][72];
    __shared__ float Opart[4][64][8];
    __shared__ float MLpart[4][64][8];
    const int qt = blockIdx.x & 31;
    const int hh = (blockIdx.x >> 5) & 7;
    const int b  = blockIdx.x >> 8;
    const int idx = ind[b];
    const int segEnd = NTOK - ind[4 + b];
    const int tid = threadIdx.x, lane = tid & 63, wave = tid >> 6;
    const int strip = wave >> 1, kh = wave & 1;
    const int l15 = lane & 15, l4 = lane >> 4;
    const int q0 = qt * 32 + strip * 16;
    const size_t tokbase = (size_t)b * NTOK;
    const bf16* vTh = vT + (((size_t)b * 8 + hh) * 32) * 1024;
    const float scale = 0.17677669529663687f;

    const bf16x8 qfrag = *(const bf16x8*)(qkvb + (tokbase + q0 + l15) * 768 + hh * 32 + l4 * 8);

    f32x4 acc_o[2];
    acc_o[0] = (f32x4)0.0f; acc_o[1] = (f32x4)0.0f;
    float mrun[4], lrun[4];
    bool v1q[4], v2q[4];
    #pragma unroll
    for (int r = 0; r < 4; ++r) {
        mrun[r] = -1e30f; lrun[r] = 0.0f;
        const int qg = q0 + l4 * 4 + r;
        v1q[r] = (qg <= idx);
        v2q[r] = (qg > idx) && (qg < segEnd);
    }

    const int kbeg = (q0 <= idx) ? 0 : (idx + 1);
    const int kend = (q0 + 15 > idx) ? segEnd : (idx + 1);
    const int t0 = kbeg & ~63;
    const int T = (kend - t0 + 63) >> 6;
    const int i0 = kh ? (T >> 1) : 0;
    const int i1 = kh ? T : (T >> 1);

    for (int i = i0; i < i1; ++i) {
        const int k0 = t0 + (i << 6);
        f32x4 sc[4];
        #pragma unroll
        for (int kt = 0; kt < 4; ++kt) {
            const bf16x8 kf = *(const bf16x8*)
                (qkvb + (tokbase + k0 + kt * 16 + l15) * 768 + 256 + hh * 32 + l4 * 8);
            sc[kt] = __builtin_amdgcn_mfma_f32_16x16x32_bf16(qfrag, kf, (f32x4)0.0f, 0, 0, 0);
        }
        float mloc[4] = {-1e30f, -1e30f, -1e30f, -1e30f};
        #pragma unroll
        for (int kt = 0; kt < 4; ++kt) {
            const int k = k0 + kt * 16 + l15;
            const bool v1k = (k <= idx);
            const bool v2k = (k > idx) && (k < segEnd);
            #pragma unroll
            for (int r = 0; r < 4; ++r) {
                const bool ok = (v1q[r] && v1k) || (v2q[r] && v2k);
                const float s = ok ? sc[kt][r] * scale : -1e30f;
                sc[kt][r] = s;
                mloc[r] = fmaxf(mloc[r], s);
            }
        }
        #pragma unroll
        for (int r = 0; r < 4; ++r) {
            mloc[r] = fmaxf(mloc[r], __shfl_xor(mloc[r], 1));
            mloc[r] = fmaxf(mloc[r], __shfl_xor(mloc[r], 2));
            mloc[r] = fmaxf(mloc[r], __shfl_xor(mloc[r], 4));
            mloc[r] = fmaxf(mloc[r], __shfl_xor(mloc[r], 8));
            const float mnew = fmaxf(mrun[r], mloc[r]);
            const float c = __expf(mrun[r] - mnew);
            mrun[r] = mnew;
            mloc[r] = c;            // corr
        }
        float psum[4] = {0.0f, 0.0f, 0.0f, 0.0f};
        #pragma unroll
        for (int kt = 0; kt < 4; ++kt) {
            #pragma unroll
            for (int r = 0; r < 4; ++r) {
                const float s = sc[kt][r];
                const float p = (s > -5e29f) ? __expf(s - mrun[r]) : 0.0f;
                psum[r] += p;
                Ps[wave][l4 * 4 + r][kt * 16 + l15] = __float2bfloat16(p);
            }
        }
        #pragma unroll
        for (int r = 0; r < 4; ++r) {
            float ps = psum[r];
            ps += __shfl_xor(ps, 1); ps += __shfl_xor(ps, 2);
            ps += __shfl_xor(ps, 4); ps += __shfl_xor(ps, 8);
            lrun[r] = lrun[r] * mloc[r] + ps;
            acc_o[0][r] *= mloc[r];
            acc_o[1][r] *= mloc[r];
        }
        #pragma unroll
        for (int ks = 0; ks < 2; ++ks) {
            const bf16x8 pa = *(const bf16x8*)&Ps[wave][l15][ks * 32 + l4 * 8];
            #pragma unroll
            for (int dt = 0; dt < 2; ++dt) {
                const bf16x8 vb = *(const bf16x8*)
                    (vTh + (size_t)(dt * 16 + l15) * 1024 + k0 + ks * 32 + l4 * 8);
                acc_o[dt] = __builtin_amdgcn_mfma_f32_16x16x32_bf16(pa, vb, acc_o[dt], 0, 0, 0);
            }
        }
    }

    #pragma unroll
    for (int r = 0; r < 4; ++r) {
        Opart[wave][lane][r]     = acc_o[0][r];
        Opart[wave][lane][4 + r] = acc_o[1][r];
        MLpart[wave][lane][r]     = mrun[r];
        MLpart[wave][lane][4 + r] = lrun[r];
    }
    __syncthreads();
    if (kh == 0) {
        #pragma unroll
        for (int r = 0; r < 4; ++r) {
            const float m1 = MLpart[wave + 1][lane][r];
            const float l1 = MLpart[wave + 1][lane][4 + r];
            const float ms = fmaxf(mrun[r], m1);
            const float c0 = __expf(mrun[r] - ms);
            const float c1 = __expf(m1 - ms);
            const float lt = lrun[r] * c0 + l1 * c1;
            const float invl = (lt > 0.0f) ? (1.0f / lt) : 0.0f;
            const float o0 = (acc_o[0][r] * c0 + Opart[wave + 1][lane][r] * c1) * invl;
            const float o1 = (acc_o[1][r] * c0 + Opart[wave + 1][lane][4 + r] * c1) * invl;
            const int qg = q0 + l4 * 4 + r;
            bf16* op = att + (tokbase + qg) * 256 + hh * 32 + l15;
            op[0]  = __float2bfloat16(o0);
            op[16] = __float2bfloat16(o1);
        }
    }
}

// ---------------- gather ----------------
__global__ __launch_bounds__(256) void gather_kernel(
    const float* __restrict__ h, const int* __restrict__ ind, float* __restrict__ out)
{
    int b = blockIdx.x;
    int tid = threadIdx.x;
    out[(b * 2 + 0) * 256 + tid] = h[(b * NTOK + 0) * 256 + tid];
    out[(b * 2 + 1) * 256 + tid] = h[(b * NTOK + ind[b] + 1) * 256 + tid];
}

extern "C" void kernel_launch(void* const* d_in, const int* in_sizes, int n_in,
                              void* d_out, int out_size, void* d_ws, size_t ws_size,
                              hipStream_t stream)
{
    const float* x    = (const float*)d_in[0];
    const int*   ind  = (const int*)d_in[2];
    const float* cls1 = (const float*)d_in[3];
    const float* cls2 = (const float*)d_in[4];
    const float* Wqkv = (const float*)d_in[5];
    const float* bqkv = (const float*)d_in[6];
    const float* Wo   = (const float*)d_in[7];
    const float* bo   = (const float*)d_in[8];
    const float* g1   = (const float*)d_in[9];
    const float* be1  = (const float*)d_in[10];
    const float* W1   = (const float*)d_in[11];
    const float* bf1  = (const float*)d_in[12];
    const float* W2   = (const float*)d_in[13];
    const float* bf2  = (const float*)d_in[14];
    const float* g2   = (const float*)d_in[15];
    const float* be2  = (const float*)d_in[16];
    float* out = (float*)d_out;

    // ---- workspace layout ----
    float* ws   = (float*)d_ws;
    float* h    = ws;                       // 1,048,576 f32
    float* tmp2 = h + 1048576;              // 2,097,152 f32 (2 split-K partials)
    bf16* hb    = (bf16*)(tmp2 + 2097152);  // 1,048,576 bf16
    bf16* qkvb  = hb + 1048576;             // 3,145,728
    bf16* vTb   = qkvb + 3145728;           // 1,048,576
    bf16* attb  = vTb + 1048576;            // 1,048,576
    bf16* ffb   = attb + 1048576;           // 8,388,608
    bf16* wqkvb = ffb + 8388608;            // 1,179,648
    bf16* wob   = wqkvb + 1179648;          // 393,216
    bf16* w1b   = wob + 393216;             // 3,145,728
    bf16* w2b   = w1b + 3145728;            // 3,145,728

    const int M = BATCH * NTOK;             // 4096

    cast4_kernel<<<7680, 256, 0, stream>>>(Wqkv, wqkvb, Wo, wob, W1, w1b, W2, w2b);
    embed_kernel<<<M, 256, 0, stream>>>(x, cls1, cls2, ind, h, hb);

    for (int l = 0; l < NLAYER; ++l) {
        const bf16*  Wqkv_l = wqkvb + (size_t)l * 196608;
        const float* bqkv_l = bqkv + (size_t)l * 768;
        const bf16*  Wo_l   = wob + (size_t)l * 65536;
        const float* bo_l   = bo + (size_t)l * 256;
        const float* g1_l   = g1 + (size_t)l * 256;
        const float* be1_l  = be1 + (size_t)l * 256;
        const bf16*  W1_l   = w1b + (size_t)l * 524288;
        const float* b1_l   = bf1 + (size_t)l * 2048;
        const bf16*  W2_l   = w2b + (size_t)l * 524288;
        const float* b2_l   = bf2 + (size_t)l * 256;
        const float* g2_l   = g2 + (size_t)l * 256;
        const float* be2_l  = be2 + (size_t)l * 256;

        // qkvb = hb @ Wqkv^T + bqkv ; V-part redirected to vT layout
        mfma_gemm<2, 4, 0, 0, 0, 1, 1, 1><<<(M / 64) * (768 / 128), 256, 0, stream>>>(
            hb, Wqkv_l, bqkv_l, nullptr, nullptr, qkvb, vTb, M, 768, 256);
        // attb = softmax(qk^T + seg-bias) v
        attn_mfma_kernel<<<BATCH * 8 * 32, 256, 0, stream>>>(qkvb, vTb, attb, ind);
        // h, hb = LN1(attb @ Wo^T + bo + h)
        gemm256_ln8_kernel<256><<<M / 16, 512, 0, stream>>>(
            attb, Wo_l, bo_l, g1_l, be1_l, h, hb);
        // ffb = relu(hb @ W1^T + b1)          (128x128 tiles, grid 512)
        mfma_gemm<4, 4, 1, 0, 0, 1, 0, 1><<<(M / 128) * (2048 / 128), 256, 0, stream>>>(
            hb, W1_l, b1_l, nullptr, nullptr, ffb, nullptr, M, 2048, 256);
        // tmp2[ks] = ffb @ W2^T partials      (split-K 2, grid 512 = 2 blocks/CU)
        mfma_gemm<2, 2, 0, 0, 1, 0, 0, 2><<<2 * (M / 64) * (256 / 64), 256, 0, stream>>>(
            ffb, W2_l, nullptr, nullptr, tmp2, nullptr, nullptr, M, 256, 2048);
        // h, hb = LN2(p0 + p1 + b2 + h)
        ln_merge_kernel<<<M / 4, 256, 0, stream>>>(
            tmp2, tmp2 + (size_t)M * 256, b2_l, g2_l, be2_l, h, hb);
    }

    gather_kernel<<<BATCH, 256, 0, stream>>>(h, ind, out);
}